// Round 1
// baseline (3005.994 us; speedup 1.0000x reference)
//
#include <hip/hip_runtime.h>
#include <math.h>

#define BATCH 4096

// ---------------- fused encoder: conv1+conv2+conv3, one block per image ----------------
__global__ __launch_bounds__(256) void enc_kernel(
    const float* __restrict__ x,
    const float* __restrict__ w_c1, const float* __restrict__ b_c1,
    const float* __restrict__ w_c2, const float* __restrict__ b_c2,
    const float* __restrict__ w_c3, const float* __restrict__ b_c3,
    float* __restrict__ h3out)
{
    __shared__ float s_x[784];     // 1x28x28
    __shared__ float s_w1[512];    // 32x1x4x4
    __shared__ float s_h1[6272];   // 32x14x14
    __shared__ float s_h2[1568];   // 32x7x7
    const int n = blockIdx.x;
    const int tid = threadIdx.x;

    for (int i = tid; i < 784; i += 256) s_x[i] = x[n * 784 + i];
    for (int i = tid; i < 512; i += 256) s_w1[i] = w_c1[i];
    __syncthreads();

    // conv1: 1->32, k4 s2 p1, 28x28 -> 14x14, relu
    for (int it = tid; it < 6272; it += 256) {
        int co = it / 196, r = it % 196;
        int oy = r / 14, ox = r % 14;
        float acc = b_c1[co];
        #pragma unroll
        for (int ky = 0; ky < 4; ++ky) {
            int iy = oy * 2 - 1 + ky;
            if ((unsigned)iy >= 28u) continue;
            #pragma unroll
            for (int kx = 0; kx < 4; ++kx) {
                int ix = ox * 2 - 1 + kx;
                if ((unsigned)ix >= 28u) continue;
                acc = fmaf(s_x[iy * 28 + ix], s_w1[co * 16 + ky * 4 + kx], acc);
            }
        }
        s_h1[it] = fmaxf(acc, 0.f);
    }
    __syncthreads();

    // conv2: 32->32, k4 s2 p1, 14x14 -> 7x7, relu. 4-way co register blocking.
    for (int it = tid; it < 392; it += 256) {
        int g = it / 49, pos = it % 49;
        int oy = pos / 7, ox = pos % 7;
        int co0 = g * 4;
        float a0 = b_c2[co0], a1 = b_c2[co0 + 1], a2 = b_c2[co0 + 2], a3 = b_c2[co0 + 3];
        for (int ky = 0; ky < 4; ++ky) {
            int iy = oy * 2 - 1 + ky;
            if ((unsigned)iy >= 14u) continue;
            for (int kx = 0; kx < 4; ++kx) {
                int ix = ox * 2 - 1 + kx;
                if ((unsigned)ix >= 14u) continue;
                const float* wp = w_c2 + co0 * 512 + ky * 4 + kx;  // + ci*16 (+j*512)
                const float* ip = s_h1 + iy * 14 + ix;             // + ci*196
                #pragma unroll 4
                for (int ci = 0; ci < 32; ++ci) {
                    float v = ip[ci * 196];
                    a0 = fmaf(v, wp[ci * 16], a0);
                    a1 = fmaf(v, wp[ci * 16 + 512], a1);
                    a2 = fmaf(v, wp[ci * 16 + 1024], a2);
                    a3 = fmaf(v, wp[ci * 16 + 1536], a3);
                }
            }
        }
        int base = co0 * 49 + pos;
        s_h2[base] = fmaxf(a0, 0.f);
        s_h2[base + 49] = fmaxf(a1, 0.f);
        s_h2[base + 98] = fmaxf(a2, 0.f);
        s_h2[base + 147] = fmaxf(a3, 0.f);
    }
    __syncthreads();

    // conv3: 32->64, k3 s2 p1, 7x7 -> 4x4, relu. exactly 256 items (16 cgroups x 16 pos)
    {
        int g = tid >> 4, pos = tid & 15;
        int oy = pos >> 2, ox = pos & 3;
        int co0 = g * 4;
        float a0 = b_c3[co0], a1 = b_c3[co0 + 1], a2 = b_c3[co0 + 2], a3 = b_c3[co0 + 3];
        for (int ky = 0; ky < 3; ++ky) {
            int iy = oy * 2 - 1 + ky;
            if ((unsigned)iy >= 7u) continue;
            for (int kx = 0; kx < 3; ++kx) {
                int ix = ox * 2 - 1 + kx;
                if ((unsigned)ix >= 7u) continue;
                const float* wp = w_c3 + co0 * 288 + ky * 3 + kx;  // + ci*9 (+j*288)
                const float* ip = s_h2 + iy * 7 + ix;              // + ci*49
                #pragma unroll 4
                for (int ci = 0; ci < 32; ++ci) {
                    float v = ip[ci * 49];
                    a0 = fmaf(v, wp[ci * 9], a0);
                    a1 = fmaf(v, wp[ci * 9 + 288], a1);
                    a2 = fmaf(v, wp[ci * 9 + 576], a2);
                    a3 = fmaf(v, wp[ci * 9 + 864], a3);
                }
            }
        }
        float* op = h3out + n * 1024 + co0 * 16 + pos;
        op[0] = fmaxf(a0, 0.f);
        op[16] = fmaxf(a1, 0.f);
        op[32] = fmaxf(a2, 0.f);
        op[48] = fmaxf(a3, 0.f);
    }
}

// ---------------- tiled NT SGEMM: C[M,N] = act(A[M,K] @ W[N,K]^T + bias) ----------------
// Requires M%64==0, N%64==0, K%16==0.
template <bool RELU>
__global__ __launch_bounds__(256) void gemm_nt(
    const float* __restrict__ A, const float* __restrict__ W,
    const float* __restrict__ bias, float* __restrict__ C,
    int M, int N, int K)
{
    __shared__ float As[16][65];
    __shared__ float Ws[16][65];
    const int tid = threadIdx.x;
    const int col0 = blockIdx.x * 64;
    const int row0 = blockIdx.y * 64;
    const int tx = tid & 15, ty = tid >> 4;
    const int lr = tid >> 2, lc = (tid & 3) * 4;
    float acc[4][4] = {};

    for (int k0 = 0; k0 < K; k0 += 16) {
        float4 av = *(const float4*)(A + (size_t)(row0 + lr) * K + k0 + lc);
        float4 wv = *(const float4*)(W + (size_t)(col0 + lr) * K + k0 + lc);
        As[lc + 0][lr] = av.x; As[lc + 1][lr] = av.y; As[lc + 2][lr] = av.z; As[lc + 3][lr] = av.w;
        Ws[lc + 0][lr] = wv.x; Ws[lc + 1][lr] = wv.y; Ws[lc + 2][lr] = wv.z; Ws[lc + 3][lr] = wv.w;
        __syncthreads();
        #pragma unroll
        for (int kk = 0; kk < 16; ++kk) {
            float a[4], b[4];
            #pragma unroll
            for (int i = 0; i < 4; ++i) a[i] = As[kk][ty * 4 + i];
            #pragma unroll
            for (int j = 0; j < 4; ++j) b[j] = Ws[kk][tx * 4 + j];
            #pragma unroll
            for (int i = 0; i < 4; ++i)
                #pragma unroll
                for (int j = 0; j < 4; ++j)
                    acc[i][j] = fmaf(a[i], b[j], acc[i][j]);
        }
        __syncthreads();
    }

    #pragma unroll
    for (int i = 0; i < 4; ++i) {
        int row = row0 + ty * 4 + i;
        float* cp = C + (size_t)row * N + col0 + tx * 4;
        float4 v;
        v.x = acc[i][0] + bias[col0 + tx * 4 + 0];
        v.y = acc[i][1] + bias[col0 + tx * 4 + 1];
        v.z = acc[i][2] + bias[col0 + tx * 4 + 2];
        v.w = acc[i][3] + bias[col0 + tx * 4 + 3];
        if (RELU) {
            v.x = fmaxf(v.x, 0.f); v.y = fmaxf(v.y, 0.f);
            v.z = fmaxf(v.z, 0.f); v.w = fmaxf(v.w, 0.f);
        }
        *(float4*)cp = v;
    }
}

// ---------------- mu / logvar heads: [B,256] -> [B,20] x2 ----------------
__global__ __launch_bounds__(256) void muls_kernel(
    const float* __restrict__ h,
    const float* __restrict__ w_mu, const float* __restrict__ b_mu,
    const float* __restrict__ w_ls, const float* __restrict__ b_ls,
    float* __restrict__ mu_out, float* __restrict__ ls_out)
{
    int idx = blockIdx.x * 256 + threadIdx.x;
    if (idx >= BATCH * 40) return;
    int i = idx / 40, j = idx % 40;
    bool is_mu = j < 20;
    int jj = is_mu ? j : j - 20;
    const float* wrow = is_mu ? (w_mu + jj * 256) : (w_ls + jj * 256);
    float acc = is_mu ? b_mu[jj] : b_ls[jj];
    const float4* hp = (const float4*)(h + (size_t)i * 256);
    const float4* wp = (const float4*)wrow;
    #pragma unroll 8
    for (int k = 0; k < 64; ++k) {
        float4 hv = hp[k], wv = wp[k];
        acc = fmaf(hv.x, wv.x, acc);
        acc = fmaf(hv.y, wv.y, acc);
        acc = fmaf(hv.z, wv.z, acc);
        acc = fmaf(hv.w, wv.w, acc);
    }
    (is_mu ? mu_out : ls_out)[i * 20 + jj] = acc;
}

// ---------------- 100-step reversing recursion + reparameterize ----------------
// mu_r amplified by 1.1^100 ~ 13780x -> do it in double to track the reference.
__global__ __launch_bounds__(256) void rev_kernel(
    const float* __restrict__ mu, const float* __restrict__ ls,
    const float* __restrict__ eps, float* __restrict__ z)
{
    int idx = blockIdx.x * 256 + threadIdx.x;
    if (idx >= BATCH * 20) return;
    double m = (double)mu[idx];
    double s = (double)ls[idx];
    #pragma unroll 4
    for (int t = 0; t < 100; ++t) {
        m += 0.1 * m;
        s += 0.05 * (exp(s) - 1.0);
    }
    z[idx] = (float)((double)eps[idx] * exp(0.5 * s) + m);
}

// ---------------- fc2: [B,20] -> [B,256], relu ----------------
__global__ __launch_bounds__(256) void fc2_kernel(
    const float* __restrict__ z, const float* __restrict__ w, const float* __restrict__ b,
    float* __restrict__ out)
{
    int idx = blockIdx.x * 256 + threadIdx.x;  // exactly B*256 threads
    int i = idx >> 8, j = idx & 255;
    float acc = b[j];
    const float* zp = z + i * 20;
    const float* wp = w + j * 20;
    #pragma unroll
    for (int k = 0; k < 20; ++k) acc = fmaf(zp[k], wp[k], acc);
    out[idx] = fmaxf(acc, 0.f);
}

// ---------------- fused decoder: deconv1+deconv2+deconv3, one block per image ----------------
__global__ __launch_bounds__(256) void dec_kernel(
    const float* __restrict__ hin,
    const float* __restrict__ w_d1, const float* __restrict__ b_d1,
    const float* __restrict__ w_d2, const float* __restrict__ b_d2,
    const float* __restrict__ w_d3, const float* __restrict__ b_d3,
    float* __restrict__ xhat)
{
    __shared__ float s_in[1024];  // 64x4x4
    __shared__ float s_d1[1568];  // 32x7x7
    __shared__ float s_d2[6272];  // 32x14x14
    __shared__ float s_w3[512];   // 32x1x4x4
    const int n = blockIdx.x, tid = threadIdx.x;

    for (int i = tid; i < 1024; i += 256) s_in[i] = hin[(size_t)n * 1024 + i];
    for (int i = tid; i < 512; i += 256) s_w3[i] = w_d3[i];
    __syncthreads();

    // deconv1: ConvT 64->32 k3 s2 p1, 4x4 -> 7x7, relu
    // gather: out[co,oy,ox] += in[ci,iy,ix]*w[ci,co,ky,kx], iy=(oy+1-ky)/2 when even & in range
    for (int it = tid; it < 392; it += 256) {
        int g = it / 49, pos = it % 49;
        int oy = pos / 7, ox = pos % 7;
        int co0 = g * 4;
        float a0 = b_d1[co0], a1 = b_d1[co0 + 1], a2 = b_d1[co0 + 2], a3 = b_d1[co0 + 3];
        for (int ky = 0; ky < 3; ++ky) {
            int t = oy + 1 - ky;
            if (t < 0 || (t & 1)) continue;
            int iy = t >> 1;
            if (iy >= 4) continue;
            for (int kx = 0; kx < 3; ++kx) {
                int u = ox + 1 - kx;
                if (u < 0 || (u & 1)) continue;
                int ix = u >> 1;
                if (ix >= 4) continue;
                const float* wp = w_d1 + co0 * 9 + ky * 3 + kx;  // + ci*288 (+j*9)
                const float* ip = s_in + iy * 4 + ix;            // + ci*16
                #pragma unroll 4
                for (int ci = 0; ci < 64; ++ci) {
                    float v = ip[ci * 16];
                    a0 = fmaf(v, wp[ci * 288], a0);
                    a1 = fmaf(v, wp[ci * 288 + 9], a1);
                    a2 = fmaf(v, wp[ci * 288 + 18], a2);
                    a3 = fmaf(v, wp[ci * 288 + 27], a3);
                }
            }
        }
        int base = co0 * 49 + pos;
        s_d1[base] = fmaxf(a0, 0.f);
        s_d1[base + 49] = fmaxf(a1, 0.f);
        s_d1[base + 98] = fmaxf(a2, 0.f);
        s_d1[base + 147] = fmaxf(a3, 0.f);
    }
    __syncthreads();

    // deconv2: ConvT 32->32 k4 s2 p1, 7x7 -> 14x14, relu
    for (int it = tid; it < 1568; it += 256) {
        int g = it / 196, pos = it % 196;
        int oy = pos / 14, ox = pos % 14;
        int co0 = g * 4;
        float a0 = b_d2[co0], a1 = b_d2[co0 + 1], a2 = b_d2[co0 + 2], a3 = b_d2[co0 + 3];
        for (int ky = 0; ky < 4; ++ky) {
            int t = oy + 1 - ky;
            if (t < 0 || (t & 1)) continue;
            int iy = t >> 1;
            if (iy >= 7) continue;
            for (int kx = 0; kx < 4; ++kx) {
                int u = ox + 1 - kx;
                if (u < 0 || (u & 1)) continue;
                int ix = u >> 1;
                if (ix >= 7) continue;
                const float* wp = w_d2 + co0 * 16 + ky * 4 + kx;  // + ci*512 (+j*16)
                const float* ip = s_d1 + iy * 7 + ix;             // + ci*49
                #pragma unroll 4
                for (int ci = 0; ci < 32; ++ci) {
                    float v = ip[ci * 49];
                    a0 = fmaf(v, wp[ci * 512], a0);
                    a1 = fmaf(v, wp[ci * 512 + 16], a1);
                    a2 = fmaf(v, wp[ci * 512 + 32], a2);
                    a3 = fmaf(v, wp[ci * 512 + 48], a3);
                }
            }
        }
        int base = co0 * 196 + pos;
        s_d2[base] = fmaxf(a0, 0.f);
        s_d2[base + 196] = fmaxf(a1, 0.f);
        s_d2[base + 392] = fmaxf(a2, 0.f);
        s_d2[base + 588] = fmaxf(a3, 0.f);
    }
    __syncthreads();

    // deconv3: ConvT 32->1 k4 s2 p1, 14x14 -> 28x28, sigmoid
    for (int it = tid; it < 784; it += 256) {
        int oy = it / 28, ox = it % 28;
        float acc = b_d3[0];
        for (int ky = 0; ky < 4; ++ky) {
            int t = oy + 1 - ky;
            if (t < 0 || (t & 1)) continue;
            int iy = t >> 1;
            if (iy >= 14) continue;
            for (int kx = 0; kx < 4; ++kx) {
                int u = ox + 1 - kx;
                if (u < 0 || (u & 1)) continue;
                int ix = u >> 1;
                if (ix >= 14) continue;
                const float* ip = s_d2 + iy * 14 + ix;   // + ci*196
                const float* wp = s_w3 + ky * 4 + kx;    // + ci*16
                #pragma unroll 4
                for (int ci = 0; ci < 32; ++ci)
                    acc = fmaf(ip[ci * 196], wp[ci * 16], acc);
            }
        }
        xhat[(size_t)n * 784 + it] = 1.f / (1.f + expf(-acc));
    }
}

extern "C" void kernel_launch(void* const* d_in, const int* in_sizes, int n_in,
                              void* d_out, int out_size, void* d_ws, size_t ws_size,
                              hipStream_t stream) {
    const float* x     = (const float*)d_in[0];
    const float* eps   = (const float*)d_in[1];
    const float* w_c1  = (const float*)d_in[2];
    const float* b_c1  = (const float*)d_in[3];
    const float* w_c2  = (const float*)d_in[4];
    const float* b_c2  = (const float*)d_in[5];
    const float* w_c3  = (const float*)d_in[6];
    const float* b_c3  = (const float*)d_in[7];
    const float* w_fc1 = (const float*)d_in[8];
    const float* b_fc1 = (const float*)d_in[9];
    const float* w_mu  = (const float*)d_in[10];
    const float* b_mu  = (const float*)d_in[11];
    const float* w_ls  = (const float*)d_in[12];
    const float* b_ls  = (const float*)d_in[13];
    const float* w_fc2 = (const float*)d_in[14];
    const float* b_fc2 = (const float*)d_in[15];
    const float* w_fc3 = (const float*)d_in[16];
    const float* b_fc3 = (const float*)d_in[17];
    const float* w_d1  = (const float*)d_in[18];
    const float* b_d1  = (const float*)d_in[19];
    const float* w_d2  = (const float*)d_in[20];
    const float* b_d2  = (const float*)d_in[21];
    const float* w_d3  = (const float*)d_in[22];
    const float* b_d3  = (const float*)d_in[23];

    float* out = (float*)d_out;
    float* x_hat  = out;                       // 4096*784
    float* mu_out = out + 4096 * 784;          // 4096*20
    float* ls_out = mu_out + 4096 * 20;        // 4096*20

    float* buf1 = (float*)d_ws;                // 4096*1024 (h3 flat / fc3 out)
    float* buf2 = buf1 + 4096 * 1024;          // 4096*256  (fc1 out / fc2 out)
    float* buf3 = buf2 + 4096 * 256;           // 4096*20   (zlat)

    // encoder convs (fused, per image)
    enc_kernel<<<BATCH, 256, 0, stream>>>(x, w_c1, b_c1, w_c2, b_c2, w_c3, b_c3, buf1);
    // fc1: [B,1024] -> [B,256] relu
    gemm_nt<true><<<dim3(256 / 64, BATCH / 64), 256, 0, stream>>>(buf1, w_fc1, b_fc1, buf2, BATCH, 256, 1024);
    // mu / logvar heads -> final output slots
    muls_kernel<<<(BATCH * 40) / 256, 256, 0, stream>>>(buf2, w_mu, b_mu, w_ls, b_ls, mu_out, ls_out);
    // 100-step reversing + reparameterize -> zlat
    rev_kernel<<<(BATCH * 20) / 256, 256, 0, stream>>>(mu_out, ls_out, eps, buf3);
    // fc2: [B,20] -> [B,256] relu
    fc2_kernel<<<BATCH, 256, 0, stream>>>(buf3, w_fc2, b_fc2, buf2);
    // fc3: [B,256] -> [B,1024] relu
    gemm_nt<true><<<dim3(1024 / 64, BATCH / 64), 256, 0, stream>>>(buf2, w_fc3, b_fc3, buf1, BATCH, 1024, 256);
    // decoder deconvs (fused, per image) -> x_hat with sigmoid
    dec_kernel<<<BATCH, 256, 0, stream>>>(buf1, w_d1, b_d1, w_d2, b_d2, w_d3, b_d3, x_hat);
}

// Round 2
// 1189.971 us; speedup vs baseline: 2.5261x; 2.5261x over previous
//
#include <hip/hip_runtime.h>
#include <math.h>

#define BATCH 4096

// ======================= weight transpose pre-pass =======================
__global__ __launch_bounds__(256) void tr_kernel(
    const float* __restrict__ w_c2, const float* __restrict__ w_c3,
    const float* __restrict__ w_d1, const float* __restrict__ w_d2,
    const float* __restrict__ w_d3,
    float* __restrict__ wt2, float* __restrict__ wt3,
    float* __restrict__ wtd1, float* __restrict__ wtd2, float* __restrict__ wtd3)
{
    int i = blockIdx.x * 256 + threadIdx.x;
    if (i < 16384) {  // w_c2 [32][32][16] -> wt2[(co*16+tap)*32+ci]
        int ci = i & 31, tap = (i >> 5) & 15, co = i >> 9;
        wt2[i] = w_c2[(co * 32 + ci) * 16 + tap];
    }
    if (i < 18432) {  // w_c3 [64][32][9] -> wt3[(co*9+tap)*32+ci]
        int ci = i & 31, r = i >> 5, tap = r % 9, co = r / 9;
        wt3[i] = w_c3[(co * 32 + ci) * 9 + tap];
    }
    if (i < 18432) {  // w_d1 [64][32][9] -> wtd1[(co*9+tap)*64+ci]
        int ci = i & 63, r = i >> 6, tap = r % 9, co = r / 9;
        wtd1[i] = w_d1[(ci * 32 + co) * 9 + tap];
    }
    if (i < 16384) {  // w_d2 [32][32][16] -> wtd2[(co*16+tap)*32+ci]
        int ci = i & 31, tap = (i >> 5) & 15, co = i >> 9;
        wtd2[i] = w_d2[(ci * 32 + co) * 16 + tap];
    }
    if (i < 512) {    // w_d3 [32][1][16] -> wtd3[tap*32+ci]
        int ci = i & 31, tap = i >> 5;
        wtd3[i] = w_d3[ci * 16 + tap];
    }
}

// ======================= fused encoder =======================
__global__ __launch_bounds__(256) void enc_kernel(
    const float* __restrict__ x,
    const float* __restrict__ w_c1, const float* __restrict__ b_c1,
    const float* __restrict__ wt2, const float* __restrict__ b_c2,
    const float* __restrict__ wt3, const float* __restrict__ b_c3,
    float* __restrict__ h3out)
{
    __shared__ float s_x[785];         // 28x28 + zero pad
    __shared__ float s_h1[197 * 33];   // [196 pos][32 ci] + ghost row
    __shared__ float s_h2[50 * 33];    // [49 pos][32 ci] + ghost row
    __shared__ float s_h3[1024];
    const int n = blockIdx.x, tid = threadIdx.x;
    const int wv = __builtin_amdgcn_readfirstlane((int)(tid >> 6));
    const int lane = tid & 63;

    for (int i = tid; i < 784; i += 256) s_x[i] = x[(size_t)n * 784 + i];
    if (tid == 0) s_x[784] = 0.f;
    for (int i = tid; i < 33; i += 256) { s_h1[196 * 33 + i] = 0.f; s_h2[49 * 33 + i] = 0.f; }
    __syncthreads();

    // ---- conv1: 1->32, k4 s2 p1, 28x28 -> 14x14, relu ----
    {
        const int co0 = wv * 8;
        for (int pos = lane; pos < 196; pos += 64) {
            int oy = pos / 14, ox = pos % 14;
            float acc[8];
            #pragma unroll
            for (int u = 0; u < 8; ++u) acc[u] = b_c1[co0 + u];
            for (int ky = 0; ky < 4; ++ky) {
                int iy = oy * 2 - 1 + ky;
                bool vy = (unsigned)iy < 28u;
                for (int kx = 0; kx < 4; ++kx) {
                    int ix = ox * 2 - 1 + kx;
                    int idx = (vy && (unsigned)ix < 28u) ? iy * 28 + ix : 784;
                    float v = s_x[idx];
                    #pragma unroll
                    for (int u = 0; u < 8; ++u)
                        acc[u] = fmaf(v, w_c1[(co0 + u) * 16 + ky * 4 + kx], acc[u]);
                }
            }
            #pragma unroll
            for (int u = 0; u < 8; ++u) s_h1[pos * 33 + co0 + u] = fmaxf(acc[u], 0.f);
        }
    }
    __syncthreads();

    // ---- conv2: 32->32, k4 s2 p1, 14x14 -> 7x7, relu ----
    {
        const int co0 = wv * 8;
        const bool act = lane < 49;
        const int p = act ? lane : 0;
        const int oy = p / 7, ox = p % 7;
        float acc[8] = {};
        for (int ky = 0; ky < 4; ++ky) {
            int iy = oy * 2 - 1 + ky;
            bool vy = (unsigned)iy < 14u;
            for (int kx = 0; kx < 4; ++kx) {
                int ix = ox * 2 - 1 + kx;
                int rbase = ((vy && (unsigned)ix < 14u) ? iy * 14 + ix : 196) * 33;
                int tap = ky * 4 + kx;
                #pragma unroll 2
                for (int cq = 0; cq < 8; ++cq) {
                    float v0 = s_h1[rbase + cq * 4 + 0], v1 = s_h1[rbase + cq * 4 + 1];
                    float v2 = s_h1[rbase + cq * 4 + 2], v3 = s_h1[rbase + cq * 4 + 3];
                    #pragma unroll
                    for (int u = 0; u < 8; ++u) {
                        const float* wp = wt2 + ((co0 + u) * 16 + tap) * 32 + cq * 4;
                        acc[u] = fmaf(v0, wp[0], acc[u]);
                        acc[u] = fmaf(v1, wp[1], acc[u]);
                        acc[u] = fmaf(v2, wp[2], acc[u]);
                        acc[u] = fmaf(v3, wp[3], acc[u]);
                    }
                }
            }
        }
        if (act) {
            #pragma unroll
            for (int u = 0; u < 8; ++u)
                s_h2[p * 33 + co0 + u] = fmaxf(acc[u] + b_c2[co0 + u], 0.f);
        }
    }
    __syncthreads();

    // ---- conv3: 32->64, k3 s2 p1, 7x7 -> 4x4, relu; ci-split x4 + shfl reduce ----
    {
        const int co0 = wv * 16;
        const int cig = lane >> 4, pos = lane & 15, ci0 = cig * 8;
        const int oy = pos >> 2, ox = pos & 3;
        float acc[16] = {};
        for (int ky = 0; ky < 3; ++ky) {
            int iy = oy * 2 - 1 + ky;
            bool vy = (unsigned)iy < 7u;
            for (int kx = 0; kx < 3; ++kx) {
                int ix = ox * 2 - 1 + kx;
                int rbase = ((vy && (unsigned)ix < 7u) ? iy * 7 + ix : 49) * 33 + ci0;
                int tap = ky * 3 + kx;
                float v[8];
                #pragma unroll
                for (int j = 0; j < 8; ++j) v[j] = s_h2[rbase + j];
                #pragma unroll
                for (int u = 0; u < 16; ++u) {
                    const float* wp = wt3 + ((co0 + u) * 9 + tap) * 32 + ci0;
                    #pragma unroll
                    for (int j = 0; j < 8; ++j) acc[u] = fmaf(v[j], wp[j], acc[u]);
                }
            }
        }
        #pragma unroll
        for (int u = 0; u < 16; ++u) {
            acc[u] += __shfl_xor(acc[u], 16, 64);
            acc[u] += __shfl_xor(acc[u], 32, 64);
        }
        if (cig == 0) {
            #pragma unroll
            for (int u = 0; u < 16; ++u)
                s_h3[(co0 + u) * 16 + pos] = fmaxf(acc[u] + b_c3[co0 + u], 0.f);
        }
    }
    __syncthreads();
    for (int i = tid; i < 1024; i += 256) h3out[(size_t)n * 1024 + i] = s_h3[i];
}

// ======================= tiled NT SGEMM =======================
template <bool RELU>
__global__ __launch_bounds__(256) void gemm_nt(
    const float* __restrict__ A, const float* __restrict__ W,
    const float* __restrict__ bias, float* __restrict__ C,
    int M, int N, int K)
{
    __shared__ float As[16][65];
    __shared__ float Ws[16][65];
    const int tid = threadIdx.x;
    const int col0 = blockIdx.x * 64;
    const int row0 = blockIdx.y * 64;
    const int tx = tid & 15, ty = tid >> 4;
    const int lr = tid >> 2, lc = (tid & 3) * 4;
    float acc[4][4] = {};

    for (int k0 = 0; k0 < K; k0 += 16) {
        float4 av = *(const float4*)(A + (size_t)(row0 + lr) * K + k0 + lc);
        float4 wv = *(const float4*)(W + (size_t)(col0 + lr) * K + k0 + lc);
        As[lc + 0][lr] = av.x; As[lc + 1][lr] = av.y; As[lc + 2][lr] = av.z; As[lc + 3][lr] = av.w;
        Ws[lc + 0][lr] = wv.x; Ws[lc + 1][lr] = wv.y; Ws[lc + 2][lr] = wv.z; Ws[lc + 3][lr] = wv.w;
        __syncthreads();
        #pragma unroll
        for (int kk = 0; kk < 16; ++kk) {
            float a[4], b[4];
            #pragma unroll
            for (int i = 0; i < 4; ++i) a[i] = As[kk][ty * 4 + i];
            #pragma unroll
            for (int j = 0; j < 4; ++j) b[j] = Ws[kk][tx * 4 + j];
            #pragma unroll
            for (int i = 0; i < 4; ++i)
                #pragma unroll
                for (int j = 0; j < 4; ++j)
                    acc[i][j] = fmaf(a[i], b[j], acc[i][j]);
        }
        __syncthreads();
    }
    #pragma unroll
    for (int i = 0; i < 4; ++i) {
        int row = row0 + ty * 4 + i;
        float* cp = C + (size_t)row * N + col0 + tx * 4;
        float4 v;
        v.x = acc[i][0] + bias[col0 + tx * 4 + 0];
        v.y = acc[i][1] + bias[col0 + tx * 4 + 1];
        v.z = acc[i][2] + bias[col0 + tx * 4 + 2];
        v.w = acc[i][3] + bias[col0 + tx * 4 + 3];
        if (RELU) {
            v.x = fmaxf(v.x, 0.f); v.y = fmaxf(v.y, 0.f);
            v.z = fmaxf(v.z, 0.f); v.w = fmaxf(v.w, 0.f);
        }
        *(float4*)cp = v;
    }
}

// ======================= mu / logvar heads =======================
__global__ __launch_bounds__(256) void muls_kernel(
    const float* __restrict__ h,
    const float* __restrict__ w_mu, const float* __restrict__ b_mu,
    const float* __restrict__ w_ls, const float* __restrict__ b_ls,
    float* __restrict__ mu_out, float* __restrict__ ls_out)
{
    int idx = blockIdx.x * 256 + threadIdx.x;
    if (idx >= BATCH * 40) return;
    int i = idx / 40, j = idx % 40;
    bool is_mu = j < 20;
    int jj = is_mu ? j : j - 20;
    const float* wrow = is_mu ? (w_mu + jj * 256) : (w_ls + jj * 256);
    float acc = is_mu ? b_mu[jj] : b_ls[jj];
    const float4* hp = (const float4*)(h + (size_t)i * 256);
    const float4* wp = (const float4*)wrow;
    #pragma unroll 8
    for (int k = 0; k < 64; ++k) {
        float4 hv = hp[k], wv = wp[k];
        acc = fmaf(hv.x, wv.x, acc);
        acc = fmaf(hv.y, wv.y, acc);
        acc = fmaf(hv.z, wv.z, acc);
        acc = fmaf(hv.w, wv.w, acc);
    }
    (is_mu ? mu_out : ls_out)[i * 20 + jj] = acc;
}

// ======================= 100-step reversing + reparameterize =======================
__global__ __launch_bounds__(256) void rev_kernel(
    const float* __restrict__ mu, const float* __restrict__ ls,
    const float* __restrict__ eps, float* __restrict__ z)
{
    int idx = blockIdx.x * 256 + threadIdx.x;
    if (idx >= BATCH * 20) return;
    double m = (double)mu[idx];
    double s = (double)ls[idx];
    #pragma unroll 4
    for (int t = 0; t < 100; ++t) {
        m += 0.1 * m;
        s += 0.05 * (exp(s) - 1.0);
    }
    z[idx] = (float)((double)eps[idx] * exp(0.5 * s) + m);
}

// ======================= fc2: [B,20] -> [B,256], relu =======================
__global__ __launch_bounds__(256) void fc2_kernel(
    const float* __restrict__ z, const float* __restrict__ w, const float* __restrict__ b,
    float* __restrict__ out)
{
    int idx = blockIdx.x * 256 + threadIdx.x;
    int i = idx >> 8, j = idx & 255;
    float acc = b[j];
    const float* zp = z + i * 20;
    const float* wp = w + j * 20;
    #pragma unroll
    for (int k = 0; k < 20; ++k) acc = fmaf(zp[k], wp[k], acc);
    out[idx] = fmaxf(acc, 0.f);
}

// ======================= fused decoder =======================
__global__ __launch_bounds__(256) void dec_kernel(
    const float* __restrict__ hin,
    const float* __restrict__ wtd1, const float* __restrict__ b_d1,
    const float* __restrict__ wtd2, const float* __restrict__ b_d2,
    const float* __restrict__ wtd3, const float* __restrict__ b_d3,
    float* __restrict__ xhat)
{
    __shared__ float s_in[17 * 65];    // [16 pos][64 ci] + ghost row
    __shared__ float s_d1[50 * 33];    // [49 pos][32 ci] + ghost row
    __shared__ float s_d2[197 * 33];   // [196 pos][32 ci] + ghost row
    const int n = blockIdx.x, tid = threadIdx.x;
    const int wv = __builtin_amdgcn_readfirstlane((int)(tid >> 6));
    const int lane = tid & 63;

    for (int t = tid; t < 1024; t += 256) {
        int p = t & 15, c = t >> 4;
        s_in[p * 65 + c] = hin[(size_t)n * 1024 + t];
    }
    for (int i = tid; i < 65; i += 256) s_in[16 * 65 + i] = 0.f;
    for (int i = tid; i < 33; i += 256) { s_d1[49 * 33 + i] = 0.f; s_d2[196 * 33 + i] = 0.f; }
    __syncthreads();

    // ---- deconv1: ConvT 64->32 k3 s2 p1, 4x4 -> 7x7, relu (4 parity classes, ci-split x4) ----
    {
        const int co0 = wv * 8;
        const int cig = lane >> 4, ci0 = cig * 16;
        const int pidx = lane & 15;
        #pragma unroll
        for (int py = 0; py < 2; ++py) {
            #pragma unroll
            for (int px = 0; px < 2; ++px) {
                const int ny = py ? 3 : 4, nx = px ? 3 : 4;
                const int P = ny * nx;
                const bool act = pidx < P;
                const int p = act ? pidx : 0;
                const int sy = p / nx, sx = p % nx;
                const int nky = py ? 2 : 1, nkx = px ? 2 : 1;
                float acc[8] = {};
                for (int it = 0; it < nky * nkx; ++it) {
                    int iky = it / nkx, ikx = it % nkx;
                    int ky = py ? (iky ? 2 : 0) : 1;
                    int kx = px ? (ikx ? 2 : 0) : 1;
                    int iy = py ? ((ky == 0) ? sy + 1 : sy) : sy;
                    int ix = px ? ((kx == 0) ? sx + 1 : sx) : sx;
                    int rbase = (iy * 4 + ix) * 65 + ci0;
                    int tap = ky * 3 + kx;
                    #pragma unroll 2
                    for (int cq = 0; cq < 4; ++cq) {
                        float v0 = s_in[rbase + cq * 4 + 0], v1 = s_in[rbase + cq * 4 + 1];
                        float v2 = s_in[rbase + cq * 4 + 2], v3 = s_in[rbase + cq * 4 + 3];
                        #pragma unroll
                        for (int u = 0; u < 8; ++u) {
                            const float* wp = wtd1 + ((co0 + u) * 9 + tap) * 64 + ci0 + cq * 4;
                            acc[u] = fmaf(v0, wp[0], acc[u]);
                            acc[u] = fmaf(v1, wp[1], acc[u]);
                            acc[u] = fmaf(v2, wp[2], acc[u]);
                            acc[u] = fmaf(v3, wp[3], acc[u]);
                        }
                    }
                }
                #pragma unroll
                for (int u = 0; u < 8; ++u) {
                    acc[u] += __shfl_xor(acc[u], 16, 64);
                    acc[u] += __shfl_xor(acc[u], 32, 64);
                }
                if (cig == 0 && act) {
                    int oy = 2 * sy + py, ox = 2 * sx + px;
                    #pragma unroll
                    for (int u = 0; u < 8; ++u)
                        s_d1[(oy * 7 + ox) * 33 + co0 + u] = fmaxf(acc[u] + b_d1[co0 + u], 0.f);
                }
            }
        }
    }
    __syncthreads();

    // ---- deconv2: ConvT 32->32 k4 s2 p1, 7x7 -> 14x14, relu (4 parity classes) ----
    {
        const int co0 = wv * 8;
        const bool act = lane < 49;
        const int p = act ? lane : 0;
        const int sy = p / 7, sx = p % 7;
        #pragma unroll
        for (int py = 0; py < 2; ++py) {
            #pragma unroll
            for (int px = 0; px < 2; ++px) {
                float acc[8] = {};
                for (int it = 0; it < 4; ++it) {
                    int iky = it >> 1, ikx = it & 1;
                    int ky = py ? (iky ? 2 : 0) : (iky ? 3 : 1);
                    int kx = px ? (ikx ? 2 : 0) : (ikx ? 3 : 1);
                    int iy = py ? ((ky == 0) ? sy + 1 : sy) : ((ky == 1) ? sy : sy - 1);
                    int ix = px ? ((kx == 0) ? sx + 1 : sx) : ((kx == 1) ? sx : sx - 1);
                    bool v = ((unsigned)iy < 7u) && ((unsigned)ix < 7u);
                    int rbase = (v ? iy * 7 + ix : 49) * 33;
                    int tap = ky * 4 + kx;
                    #pragma unroll 2
                    for (int cq = 0; cq < 8; ++cq) {
                        float v0 = s_d1[rbase + cq * 4 + 0], v1 = s_d1[rbase + cq * 4 + 1];
                        float v2 = s_d1[rbase + cq * 4 + 2], v3 = s_d1[rbase + cq * 4 + 3];
                        #pragma unroll
                        for (int u = 0; u < 8; ++u) {
                            const float* wp = wtd2 + ((co0 + u) * 16 + tap) * 32 + cq * 4;
                            acc[u] = fmaf(v0, wp[0], acc[u]);
                            acc[u] = fmaf(v1, wp[1], acc[u]);
                            acc[u] = fmaf(v2, wp[2], acc[u]);
                            acc[u] = fmaf(v3, wp[3], acc[u]);
                        }
                    }
                }
                if (act) {
                    int oy = 2 * sy + py, ox = 2 * sx + px;
                    #pragma unroll
                    for (int u = 0; u < 8; ++u)
                        s_d2[(oy * 14 + ox) * 33 + co0 + u] = fmaxf(acc[u] + b_d2[co0 + u], 0.f);
                }
            }
        }
    }
    __syncthreads();

    // ---- deconv3: ConvT 32->1 k4 s2 p1, 14x14 -> 28x28, sigmoid (4 parity classes) ----
    {
        const bool act = tid < 196;
        const int p = act ? tid : 0;
        const int sy = p / 14, sx = p % 14;
        #pragma unroll
        for (int py = 0; py < 2; ++py) {
            #pragma unroll
            for (int px = 0; px < 2; ++px) {
                float acc = 0.f;
                for (int it = 0; it < 4; ++it) {
                    int iky = it >> 1, ikx = it & 1;
                    int ky = py ? (iky ? 2 : 0) : (iky ? 3 : 1);
                    int kx = px ? (ikx ? 2 : 0) : (ikx ? 3 : 1);
                    int iy = py ? ((ky == 0) ? sy + 1 : sy) : ((ky == 1) ? sy : sy - 1);
                    int ix = px ? ((kx == 0) ? sx + 1 : sx) : ((kx == 1) ? sx : sx - 1);
                    bool v = ((unsigned)iy < 14u) && ((unsigned)ix < 14u);
                    int rbase = (v ? iy * 14 + ix : 196) * 33;
                    int tap = ky * 4 + kx;
                    #pragma unroll 2
                    for (int cq = 0; cq < 8; ++cq) {
                        #pragma unroll
                        for (int j = 0; j < 4; ++j)
                            acc = fmaf(s_d2[rbase + cq * 4 + j], wtd3[tap * 32 + cq * 4 + j], acc);
                    }
                }
                if (act) {
                    int oy = 2 * sy + py, ox = 2 * sx + px;
                    xhat[(size_t)n * 784 + oy * 28 + ox] = 1.f / (1.f + expf(-(acc + b_d3[0])));
                }
            }
        }
    }
}

extern "C" void kernel_launch(void* const* d_in, const int* in_sizes, int n_in,
                              void* d_out, int out_size, void* d_ws, size_t ws_size,
                              hipStream_t stream) {
    const float* x     = (const float*)d_in[0];
    const float* eps   = (const float*)d_in[1];
    const float* w_c1  = (const float*)d_in[2];
    const float* b_c1  = (const float*)d_in[3];
    const float* w_c2  = (const float*)d_in[4];
    const float* b_c2  = (const float*)d_in[5];
    const float* w_c3  = (const float*)d_in[6];
    const float* b_c3  = (const float*)d_in[7];
    const float* w_fc1 = (const float*)d_in[8];
    const float* b_fc1 = (const float*)d_in[9];
    const float* w_mu  = (const float*)d_in[10];
    const float* b_mu  = (const float*)d_in[11];
    const float* w_ls  = (const float*)d_in[12];
    const float* b_ls  = (const float*)d_in[13];
    const float* w_fc2 = (const float*)d_in[14];
    const float* b_fc2 = (const float*)d_in[15];
    const float* w_fc3 = (const float*)d_in[16];
    const float* b_fc3 = (const float*)d_in[17];
    const float* w_d1  = (const float*)d_in[18];
    const float* b_d1  = (const float*)d_in[19];
    const float* w_d2  = (const float*)d_in[20];
    const float* b_d2  = (const float*)d_in[21];
    const float* w_d3  = (const float*)d_in[22];
    const float* b_d3  = (const float*)d_in[23];

    float* out = (float*)d_out;
    float* x_hat  = out;                  // 4096*784
    float* mu_out = out + 4096 * 784;     // 4096*20
    float* ls_out = mu_out + 4096 * 20;   // 4096*20

    float* buf1 = (float*)d_ws;           // 4096*1024 (h3 / fc3 out); zlat reuses its head
    float* buf2 = buf1 + 4096 * 1024;     // 4096*256  (fc1 out / fc2 out)
    float* zlat = buf1;                   // 4096*20, live only between rev and fc2
    float* wt2  = buf2 + 4096 * 256;      // 16384
    float* wt3  = wt2 + 16384;            // 18432
    float* wtd1 = wt3 + 18432;            // 18432
    float* wtd2 = wtd1 + 18432;           // 16384
    float* wtd3 = wtd2 + 16384;           // 512

    tr_kernel<<<72, 256, 0, stream>>>(w_c2, w_c3, w_d1, w_d2, w_d3, wt2, wt3, wtd1, wtd2, wtd3);
    enc_kernel<<<BATCH, 256, 0, stream>>>(x, w_c1, b_c1, wt2, b_c2, wt3, b_c3, buf1);
    gemm_nt<true><<<dim3(256 / 64, BATCH / 64), 256, 0, stream>>>(buf1, w_fc1, b_fc1, buf2, BATCH, 256, 1024);
    muls_kernel<<<(BATCH * 40) / 256, 256, 0, stream>>>(buf2, w_mu, b_mu, w_ls, b_ls, mu_out, ls_out);
    rev_kernel<<<(BATCH * 20) / 256, 256, 0, stream>>>(mu_out, ls_out, eps, zlat);
    fc2_kernel<<<BATCH, 256, 0, stream>>>(zlat, w_fc2, b_fc2, buf2);
    gemm_nt<true><<<dim3(1024 / 64, BATCH / 64), 256, 0, stream>>>(buf2, w_fc3, b_fc3, buf1, BATCH, 1024, 256);
    dec_kernel<<<BATCH, 256, 0, stream>>>(buf1, wtd1, b_d1, wtd2, b_d2, wtd3, b_d3, x_hat);
}

// Round 3
// 823.474 us; speedup vs baseline: 3.6504x; 1.4451x over previous
//
#include <hip/hip_runtime.h>
#include <math.h>

#define BATCH 4096

// ======================= weight transpose pre-pass =======================
// All conv/deconv weights -> [co][tap][ci] (ci contiguous, float4-loadable).
__global__ __launch_bounds__(256) void tr_kernel(
    const float* __restrict__ w_c2, const float* __restrict__ w_c3,
    const float* __restrict__ w_d1, const float* __restrict__ w_d2,
    const float* __restrict__ w_d3,
    float* __restrict__ wt2, float* __restrict__ wt3,
    float* __restrict__ wtd1, float* __restrict__ wtd2, float* __restrict__ wtd3)
{
    int i = blockIdx.x * 256 + threadIdx.x;
    if (i < 16384) {  // w_c2 [32][32][16] -> wt2[(co*16+tap)*32+ci]
        int ci = i & 31, tap = (i >> 5) & 15, co = i >> 9;
        wt2[i] = w_c2[(co * 32 + ci) * 16 + tap];
    }
    if (i < 18432) {  // w_c3 [64][32][9] -> wt3[(co*9+tap)*32+ci]
        int ci = i & 31, r = i >> 5, tap = r % 9, co = r / 9;
        wt3[i] = w_c3[(co * 32 + ci) * 9 + tap];
    }
    if (i < 18432) {  // w_d1 [64][32][9] -> wtd1[(co*9+tap)*64+ci]
        int ci = i & 63, r = i >> 6, tap = r % 9, co = r / 9;
        wtd1[i] = w_d1[(ci * 32 + co) * 9 + tap];
    }
    if (i < 16384) {  // w_d2 [32][32][16] -> wtd2[(co*16+tap)*32+ci]
        int ci = i & 31, tap = (i >> 5) & 15, co = i >> 9;
        wtd2[i] = w_d2[(ci * 32 + co) * 16 + tap];
    }
    if (i < 512) {    // w_d3 [32][1][16] -> wtd3[tap*32+ci]
        int ci = i & 31, tap = i >> 5;
        wtd3[i] = w_d3[ci * 16 + tap];
    }
}

// ======================= fused encoder =======================
// Weights in per-lane VGPRs; activations broadcast from LDS (uniform-pos b128).
// Lane mapping per conv: lane = co_sub | (ci_group << k); butterfly reduce over
// ci_groups. LDS rows stride 36 (16B-aligned, conflict-free) with ghost rows.
__global__ __launch_bounds__(256) void enc_kernel(
    const float* __restrict__ x,
    const float* __restrict__ w_c1, const float* __restrict__ b_c1,
    const float* __restrict__ wt2, const float* __restrict__ b_c2,
    const float* __restrict__ wt3, const float* __restrict__ b_c3,
    float* __restrict__ h3out)
{
    __shared__ __align__(16) float buf[9480];
    float* s_h1 = buf;            // [196+1][36]  (ghost row 196)
    float* s_h3 = buf;            // [1024] reuses h1 region after conv2
    float* s_x  = buf + 7092;     // [784+1]     (ghost at 784)
    float* s_h2 = buf + 7880;     // [49+1][32]  (ghost row 49)

    const int n = blockIdx.x, tid = threadIdx.x;
    const int wv = __builtin_amdgcn_readfirstlane((int)(tid >> 6));
    const int lane = tid & 63;
    const int co0 = wv * 8;
    const int co_sub = lane & 7;      // conv1/conv2 co within wave
    const int cig = lane >> 3;        // conv2 ci group (4 ci each); conv1 pos group

    // --- preload conv1 (16) + conv2 (64) weights into VGPRs ---
    float w1[16];
    #pragma unroll
    for (int k = 0; k < 4; ++k)
        *(float4*)(w1 + 4 * k) = *(const float4*)(w_c1 + (co0 + co_sub) * 16 + 4 * k);
    float w2[16][4];
    #pragma unroll
    for (int tap = 0; tap < 16; ++tap)
        *(float4*)(w2[tap]) = *(const float4*)(wt2 + ((co0 + co_sub) * 16 + tap) * 32 + cig * 4);
    const float b1 = b_c1[co0 + co_sub];
    const float b2 = b_c2[co0 + co_sub];

    for (int i = tid; i < 784; i += 256) s_x[i] = x[(size_t)n * 784 + i];
    if (tid == 0) s_x[784] = 0.f;
    for (int i = tid; i < 36; i += 256) s_h1[196 * 36 + i] = 0.f;
    for (int i = tid; i < 32; i += 256) s_h2[49 * 32 + i] = 0.f;
    __syncthreads();

    // ---- conv1: 1->32, k4 s2 p1, 28x28 -> 14x14, relu ----
    // lane (co_sub, pg): position pg+8t, one co each; x broadcast to 8 lanes.
    for (int t = 0; t < 25; ++t) {
        int pos = cig + 8 * t;
        bool val = pos < 196;
        int p = val ? pos : 0;
        int oy = p / 14, ox = p % 14;
        float acc = b1;
        #pragma unroll
        for (int ky = 0; ky < 4; ++ky) {
            int iy = oy * 2 - 1 + ky;
            bool vy = (unsigned)iy < 28u;
            #pragma unroll
            for (int kx = 0; kx < 4; ++kx) {
                int ix = ox * 2 - 1 + kx;
                int idx = (vy && (unsigned)ix < 28u) ? iy * 28 + ix : 784;
                acc = fmaf(s_x[idx], w1[ky * 4 + kx], acc);
            }
        }
        if (val) s_h1[p * 36 + co0 + co_sub] = fmaxf(acc, 0.f);
    }
    __syncthreads();

    // ---- conv2: 32->32, k4 s2 p1, 14x14 -> 7x7, relu ----
    // all 64 lanes: 8 co x 8 ci-groups; b128 broadcast reads; butterfly over cig.
    for (int oy = 0; oy < 7; ++oy) {
        int iy0 = oy * 2 - 1;
        for (int ox = 0; ox < 7; ++ox) {
            float acc = 0.f;
            #pragma unroll
            for (int ky = 0; ky < 4; ++ky) {
                int iy = iy0 + ky;
                bool vy = (unsigned)iy < 14u;
                #pragma unroll
                for (int kx = 0; kx < 4; ++kx) {
                    int ix = ox * 2 - 1 + kx;
                    int rb = ((vy && (unsigned)ix < 14u) ? iy * 14 + ix : 196) * 36;
                    float4 v = *(const float4*)(s_h1 + rb + cig * 4);
                    acc = fmaf(v.x, w2[ky * 4 + kx][0], acc);
                    acc = fmaf(v.y, w2[ky * 4 + kx][1], acc);
                    acc = fmaf(v.z, w2[ky * 4 + kx][2], acc);
                    acc = fmaf(v.w, w2[ky * 4 + kx][3], acc);
                }
            }
            acc += __shfl_xor(acc, 8);
            acc += __shfl_xor(acc, 16);
            acc += __shfl_xor(acc, 32);
            if (cig == 0)
                s_h2[(oy * 7 + ox) * 32 + co0 + co_sub] = fmaxf(acc + b2, 0.f);
        }
    }
    __syncthreads();

    // ---- conv3: 32->64, k3 s2 p1, 7x7 -> 4x4, relu ----
    // lane = co_sub3 (16) | cig3 (4 groups of 8 ci); butterfly over cig3.
    {
        const int co03 = wv * 16;
        const int co_sub3 = lane & 15;
        const int cig3 = lane >> 4;
        const int ci0 = cig3 * 8;
        float w3[9][8];
        #pragma unroll
        for (int tap = 0; tap < 9; ++tap) {
            *(float4*)(w3[tap])     = *(const float4*)(wt3 + ((co03 + co_sub3) * 9 + tap) * 32 + ci0);
            *(float4*)(w3[tap] + 4) = *(const float4*)(wt3 + ((co03 + co_sub3) * 9 + tap) * 32 + ci0 + 4);
        }
        const float b3 = b_c3[co03 + co_sub3];
        for (int pos = 0; pos < 16; ++pos) {
            int oy = pos >> 2, ox = pos & 3;
            float acc = 0.f;
            #pragma unroll
            for (int ky = 0; ky < 3; ++ky) {
                int iy = oy * 2 - 1 + ky;
                bool vy = (unsigned)iy < 7u;
                #pragma unroll
                for (int kx = 0; kx < 3; ++kx) {
                    int ix = ox * 2 - 1 + kx;
                    int rb = ((vy && (unsigned)ix < 7u) ? iy * 7 + ix : 49) * 32;
                    float4 va = *(const float4*)(s_h2 + rb + ci0);
                    float4 vb = *(const float4*)(s_h2 + rb + ci0 + 4);
                    int tp = ky * 3 + kx;
                    acc = fmaf(va.x, w3[tp][0], acc);
                    acc = fmaf(va.y, w3[tp][1], acc);
                    acc = fmaf(va.z, w3[tp][2], acc);
                    acc = fmaf(va.w, w3[tp][3], acc);
                    acc = fmaf(vb.x, w3[tp][4], acc);
                    acc = fmaf(vb.y, w3[tp][5], acc);
                    acc = fmaf(vb.z, w3[tp][6], acc);
                    acc = fmaf(vb.w, w3[tp][7], acc);
                }
            }
            acc += __shfl_xor(acc, 16);
            acc += __shfl_xor(acc, 32);
            if (cig3 == 0)
                s_h3[(co03 + co_sub3) * 16 + pos] = fmaxf(acc + b3, 0.f);
        }
    }
    __syncthreads();
    for (int i = tid; i < 1024; i += 256) h3out[(size_t)n * 1024 + i] = s_h3[i];
}

// ======================= tiled NT SGEMM =======================
template <bool RELU>
__global__ __launch_bounds__(256) void gemm_nt(
    const float* __restrict__ A, const float* __restrict__ W,
    const float* __restrict__ bias, float* __restrict__ C,
    int M, int N, int K)
{
    __shared__ float As[16][65];
    __shared__ float Ws[16][65];
    const int tid = threadIdx.x;
    const int col0 = blockIdx.x * 64;
    const int row0 = blockIdx.y * 64;
    const int tx = tid & 15, ty = tid >> 4;
    const int lr = tid >> 2, lc = (tid & 3) * 4;
    float acc[4][4] = {};

    for (int k0 = 0; k0 < K; k0 += 16) {
        float4 av = *(const float4*)(A + (size_t)(row0 + lr) * K + k0 + lc);
        float4 wv = *(const float4*)(W + (size_t)(col0 + lr) * K + k0 + lc);
        As[lc + 0][lr] = av.x; As[lc + 1][lr] = av.y; As[lc + 2][lr] = av.z; As[lc + 3][lr] = av.w;
        Ws[lc + 0][lr] = wv.x; Ws[lc + 1][lr] = wv.y; Ws[lc + 2][lr] = wv.z; Ws[lc + 3][lr] = wv.w;
        __syncthreads();
        #pragma unroll
        for (int kk = 0; kk < 16; ++kk) {
            float a[4], b[4];
            #pragma unroll
            for (int i = 0; i < 4; ++i) a[i] = As[kk][ty * 4 + i];
            #pragma unroll
            for (int j = 0; j < 4; ++j) b[j] = Ws[kk][tx * 4 + j];
            #pragma unroll
            for (int i = 0; i < 4; ++i)
                #pragma unroll
                for (int j = 0; j < 4; ++j)
                    acc[i][j] = fmaf(a[i], b[j], acc[i][j]);
        }
        __syncthreads();
    }
    #pragma unroll
    for (int i = 0; i < 4; ++i) {
        int row = row0 + ty * 4 + i;
        float* cp = C + (size_t)row * N + col0 + tx * 4;
        float4 v;
        v.x = acc[i][0] + bias[col0 + tx * 4 + 0];
        v.y = acc[i][1] + bias[col0 + tx * 4 + 1];
        v.z = acc[i][2] + bias[col0 + tx * 4 + 2];
        v.w = acc[i][3] + bias[col0 + tx * 4 + 3];
        if (RELU) {
            v.x = fmaxf(v.x, 0.f); v.y = fmaxf(v.y, 0.f);
            v.z = fmaxf(v.z, 0.f); v.w = fmaxf(v.w, 0.f);
        }
        *(float4*)cp = v;
    }
}

// ======================= mu / logvar heads =======================
__global__ __launch_bounds__(256) void muls_kernel(
    const float* __restrict__ h,
    const float* __restrict__ w_mu, const float* __restrict__ b_mu,
    const float* __restrict__ w_ls, const float* __restrict__ b_ls,
    float* __restrict__ mu_out, float* __restrict__ ls_out)
{
    int idx = blockIdx.x * 256 + threadIdx.x;
    if (idx >= BATCH * 40) return;
    int i = idx / 40, j = idx % 40;
    bool is_mu = j < 20;
    int jj = is_mu ? j : j - 20;
    const float* wrow = is_mu ? (w_mu + jj * 256) : (w_ls + jj * 256);
    float acc = is_mu ? b_mu[jj] : b_ls[jj];
    const float4* hp = (const float4*)(h + (size_t)i * 256);
    const float4* wp = (const float4*)wrow;
    #pragma unroll 8
    for (int k = 0; k < 64; ++k) {
        float4 hv = hp[k], wv = wp[k];
        acc = fmaf(hv.x, wv.x, acc);
        acc = fmaf(hv.y, wv.y, acc);
        acc = fmaf(hv.z, wv.z, acc);
        acc = fmaf(hv.w, wv.w, acc);
    }
    (is_mu ? mu_out : ls_out)[i * 20 + jj] = acc;
}

// ======================= 100-step reversing + reparameterize =======================
__global__ __launch_bounds__(256) void rev_kernel(
    const float* __restrict__ mu, const float* __restrict__ ls,
    const float* __restrict__ eps, float* __restrict__ z)
{
    int idx = blockIdx.x * 256 + threadIdx.x;
    if (idx >= BATCH * 20) return;
    double m = (double)mu[idx];
    double s = (double)ls[idx];
    #pragma unroll 4
    for (int t = 0; t < 100; ++t) {
        m += 0.1 * m;
        s += 0.05 * (exp(s) - 1.0);
    }
    z[idx] = (float)((double)eps[idx] * exp(0.5 * s) + m);
}

// ======================= fc2: [B,20] -> [B,256], relu =======================
__global__ __launch_bounds__(256) void fc2_kernel(
    const float* __restrict__ z, const float* __restrict__ w, const float* __restrict__ b,
    float* __restrict__ out)
{
    int idx = blockIdx.x * 256 + threadIdx.x;
    int i = idx >> 8, j = idx & 255;
    float acc = b[j];
    const float* zp = z + i * 20;
    const float* wp = w + j * 20;
    #pragma unroll
    for (int k = 0; k < 20; ++k) acc = fmaf(zp[k], wp[k], acc);
    out[idx] = fmaxf(acc, 0.f);
}

// ======================= fused decoder =======================
__global__ __launch_bounds__(256) void dec_kernel(
    const float* __restrict__ hin,
    const float* __restrict__ wtd1, const float* __restrict__ b_d1,
    const float* __restrict__ wtd2, const float* __restrict__ b_d2,
    const float* __restrict__ wtd3, const float* __restrict__ b_d3,
    float* __restrict__ xhat)
{
    __shared__ __align__(16) float dbuf[9780];
    float* s_d2   = dbuf;            // [196+1][36] (ghost row 196)
    float* s_d1   = dbuf + 7092;     // [49+1][32]  (ghost row 49)
    float* s_in   = dbuf + 8692;     // [17][64]
    float* s_part = dbuf + 8692;     // [4][196] reuses s_in after deconv1

    const int n = blockIdx.x, tid = threadIdx.x;
    const int wv = __builtin_amdgcn_readfirstlane((int)(tid >> 6));
    const int lane = tid & 63;
    const int co0 = wv * 8;
    const int co_sub = lane & 7;

    for (int t = tid; t < 1024; t += 256) {
        int p = t & 15, c = t >> 4;
        s_in[p * 64 + c] = hin[(size_t)n * 1024 + t];
    }
    for (int i = tid; i < 32; i += 256) s_d1[49 * 32 + i] = 0.f;
    for (int i = tid; i < 36; i += 256) s_d2[196 * 36 + i] = 0.f;

    // ---- deconv1 weights: lane = co_sub(8) | cig8(8 groups of 8 ci) ----
    const int cig8 = lane >> 3;
    {
        const int ci0 = cig8 * 8;
        float wd1[9][8];
        #pragma unroll
        for (int tap = 0; tap < 9; ++tap) {
            *(float4*)(wd1[tap])     = *(const float4*)(wtd1 + ((co0 + co_sub) * 9 + tap) * 64 + ci0);
            *(float4*)(wd1[tap] + 4) = *(const float4*)(wtd1 + ((co0 + co_sub) * 9 + tap) * 64 + ci0 + 4);
        }
        const float bd1 = b_d1[co0 + co_sub];
        __syncthreads();

        // ConvT 64->32 k3 s2 p1, 4x4 -> 7x7, relu; 4 parity classes, no ghosts.
        #pragma unroll
        for (int py = 0; py < 2; ++py) {
            #pragma unroll
            for (int px = 0; px < 2; ++px) {
                const int ny = 4 - py, nx = 4 - px;
                for (int sy = 0; sy < ny; ++sy) {
                    for (int sx = 0; sx < nx; ++sx) {
                        float acc = 0.f;
                        #pragma unroll
                        for (int a = 0; a <= 1; ++a) {
                            if (a == 1 && py == 0) continue;
                            int ky = py ? (a ? 2 : 0) : 1;
                            int iy = py ? (a ? sy : sy + 1) : sy;
                            #pragma unroll
                            for (int b = 0; b <= 1; ++b) {
                                if (b == 1 && px == 0) continue;
                                int kx = px ? (b ? 2 : 0) : 1;
                                int ix = px ? (b ? sx : sx + 1) : sx;
                                int rb = (iy * 4 + ix) * 64 + cig8 * 8;
                                float4 va = *(const float4*)(s_in + rb);
                                float4 vb = *(const float4*)(s_in + rb + 4);
                                int tp = ky * 3 + kx;
                                acc = fmaf(va.x, wd1[tp][0], acc);
                                acc = fmaf(va.y, wd1[tp][1], acc);
                                acc = fmaf(va.z, wd1[tp][2], acc);
                                acc = fmaf(va.w, wd1[tp][3], acc);
                                acc = fmaf(vb.x, wd1[tp][4], acc);
                                acc = fmaf(vb.y, wd1[tp][5], acc);
                                acc = fmaf(vb.z, wd1[tp][6], acc);
                                acc = fmaf(vb.w, wd1[tp][7], acc);
                            }
                        }
                        acc += __shfl_xor(acc, 8);
                        acc += __shfl_xor(acc, 16);
                        acc += __shfl_xor(acc, 32);
                        if (cig8 == 0)
                            s_d1[((2 * sy + py) * 7 + 2 * sx + px) * 32 + co0 + co_sub] =
                                fmaxf(acc + bd1, 0.f);
                    }
                }
            }
        }
    }
    __syncthreads();

    // ---- deconv2: ConvT 32->32 k4 s2 p1, 7x7 -> 14x14, relu ----
    // lane = co_sub(8) | cig(8 groups of 4 ci); 3x3 neighborhood shared by 4 classes.
    {
        const int cig = lane >> 3;
        float wd2[16][4];
        #pragma unroll
        for (int tap = 0; tap < 16; ++tap)
            *(float4*)(wd2[tap]) = *(const float4*)(wtd2 + ((co0 + co_sub) * 16 + tap) * 32 + cig * 4);
        const float bd2 = b_d2[co0 + co_sub];

        for (int sy = 0; sy < 7; ++sy) {
            for (int sx = 0; sx < 7; ++sx) {
                float4 v[3][3];
                #pragma unroll
                for (int dy = -1; dy <= 1; ++dy) {
                    bool vy = (unsigned)(sy + dy) < 7u;
                    #pragma unroll
                    for (int dx = -1; dx <= 1; ++dx) {
                        int rb = ((vy && (unsigned)(sx + dx) < 7u) ? (sy + dy) * 7 + sx + dx : 49) * 32;
                        v[dy + 1][dx + 1] = *(const float4*)(s_d1 + rb + cig * 4);
                    }
                }
                #pragma unroll
                for (int py = 0; py < 2; ++py) {
                    #pragma unroll
                    for (int px = 0; px < 2; ++px) {
                        float acc = 0.f;
                        #pragma unroll
                        for (int a = 0; a < 2; ++a) {
                            int ky = py ? (a ? 2 : 0) : (a ? 3 : 1);
                            int dy = py ? (a ? 0 : 1) : (a ? -1 : 0);
                            #pragma unroll
                            for (int b = 0; b < 2; ++b) {
                                int kx = px ? (b ? 2 : 0) : (b ? 3 : 1);
                                int dx = px ? (b ? 0 : 1) : (b ? -1 : 0);
                                int tp = ky * 4 + kx;
                                float4 vv = v[1 + dy][1 + dx];
                                acc = fmaf(vv.x, wd2[tp][0], acc);
                                acc = fmaf(vv.y, wd2[tp][1], acc);
                                acc = fmaf(vv.z, wd2[tp][2], acc);
                                acc = fmaf(vv.w, wd2[tp][3], acc);
                            }
                        }
                        acc += __shfl_xor(acc, 8);
                        acc += __shfl_xor(acc, 16);
                        acc += __shfl_xor(acc, 32);
                        if (cig == 0)
                            s_d2[((2 * sy + py) * 14 + 2 * sx + px) * 36 + co0 + co_sub] =
                                fmaxf(acc + bd2, 0.f);
                    }
                }
            }
        }
    }
    __syncthreads();

    // ---- deconv3: ConvT 32->1 k4 s2 p1, 14x14 -> 28x28, sigmoid ----
    // 4 classes sequential; wave wv owns ci [wv*8, wv*8+8); lane = spos chunk.
    {
        const int ci0 = wv * 8;
        const float bd3 = b_d3[0];
        #pragma unroll
        for (int py = 0; py < 2; ++py) {
            #pragma unroll
            for (int px = 0; px < 2; ++px) {
                float w3r[2][2][8];
                #pragma unroll
                for (int a = 0; a < 2; ++a) {
                    int ky = py ? (a ? 2 : 0) : (a ? 3 : 1);
                    #pragma unroll
                    for (int b = 0; b < 2; ++b) {
                        int kx = px ? (b ? 2 : 0) : (b ? 3 : 1);
                        *(float4*)(w3r[a][b])     = *(const float4*)(wtd3 + (ky * 4 + kx) * 32 + ci0);
                        *(float4*)(w3r[a][b] + 4) = *(const float4*)(wtd3 + (ky * 4 + kx) * 32 + ci0 + 4);
                    }
                }
                for (int t = 0; t < 4; ++t) {
                    int spos = t * 64 + lane;
                    bool val = spos < 196;
                    int sp = val ? spos : 0;
                    int sy = sp / 14, sx = sp % 14;
                    float acc = 0.f;
                    #pragma unroll
                    for (int a = 0; a < 2; ++a) {
                        int row = sy + py - a;
                        bool vy = (unsigned)row < 14u;
                        #pragma unroll
                        for (int b = 0; b < 2; ++b) {
                            int col = sx + px - b;
                            int rb = ((vy && (unsigned)col < 14u) ? row * 14 + col : 196) * 36 + ci0;
                            float4 va = *(const float4*)(s_d2 + rb);
                            float4 vb = *(const float4*)(s_d2 + rb + 4);
                            acc = fmaf(va.x, w3r[a][b][0], acc);
                            acc = fmaf(va.y, w3r[a][b][1], acc);
                            acc = fmaf(va.z, w3r[a][b][2], acc);
                            acc = fmaf(va.w, w3r[a][b][3], acc);
                            acc = fmaf(vb.x, w3r[a][b][4], acc);
                            acc = fmaf(vb.y, w3r[a][b][5], acc);
                            acc = fmaf(vb.z, w3r[a][b][6], acc);
                            acc = fmaf(vb.w, w3r[a][b][7], acc);
                        }
                    }
                    if (val) s_part[wv * 196 + sp] = acc;
                }
                __syncthreads();
                if (tid < 196) {
                    float s = s_part[tid] + s_part[196 + tid] + s_part[392 + tid] + s_part[588 + tid];
                    int sy = tid / 14, sx = tid % 14;
                    xhat[(size_t)n * 784 + (2 * sy + py) * 28 + 2 * sx + px] =
                        1.f / (1.f + expf(-(s + bd3)));
                }
                __syncthreads();
            }
        }
    }
}

extern "C" void kernel_launch(void* const* d_in, const int* in_sizes, int n_in,
                              void* d_out, int out_size, void* d_ws, size_t ws_size,
                              hipStream_t stream) {
    const float* x     = (const float*)d_in[0];
    const float* eps   = (const float*)d_in[1];
    const float* w_c1  = (const float*)d_in[2];
    const float* b_c1  = (const float*)d_in[3];
    const float* w_c2  = (const float*)d_in[4];
    const float* b_c2  = (const float*)d_in[5];
    const float* w_c3  = (const float*)d_in[6];
    const float* b_c3  = (const float*)d_in[7];
    const float* w_fc1 = (const float*)d_in[8];
    const float* b_fc1 = (const float*)d_in[9];
    const float* w_mu  = (const float*)d_in[10];
    const float* b_mu  = (const float*)d_in[11];
    const float* w_ls  = (const float*)d_in[12];
    const float* b_ls  = (const float*)d_in[13];
    const float* w_fc2 = (const float*)d_in[14];
    const float* b_fc2 = (const float*)d_in[15];
    const float* w_fc3 = (const float*)d_in[16];
    const float* b_fc3 = (const float*)d_in[17];
    const float* w_d1  = (const float*)d_in[18];
    const float* b_d1  = (const float*)d_in[19];
    const float* w_d2  = (const float*)d_in[20];
    const float* b_d2  = (const float*)d_in[21];
    const float* w_d3  = (const float*)d_in[22];
    const float* b_d3  = (const float*)d_in[23];

    float* out = (float*)d_out;
    float* x_hat  = out;                  // 4096*784
    float* mu_out = out + 4096 * 784;     // 4096*20
    float* ls_out = mu_out + 4096 * 20;   // 4096*20

    float* buf1 = (float*)d_ws;           // 4096*1024 (h3 / fc3 out); zlat reuses head
    float* buf2 = buf1 + 4096 * 1024;     // 4096*256  (fc1 out / fc2 out)
    float* zlat = buf1;                   // 4096*20, live only between rev and fc2
    float* wt2  = buf2 + 4096 * 256;      // 16384
    float* wt3  = wt2 + 16384;            // 18432
    float* wtd1 = wt3 + 18432;            // 18432
    float* wtd2 = wtd1 + 18432;           // 16384
    float* wtd3 = wtd2 + 16384;           // 512

    tr_kernel<<<72, 256, 0, stream>>>(w_c2, w_c3, w_d1, w_d2, w_d3, wt2, wt3, wtd1, wtd2, wtd3);
    enc_kernel<<<BATCH, 256, 0, stream>>>(x, w_c1, b_c1, wt2, b_c2, wt3, b_c3, buf1);
    gemm_nt<true><<<dim3(256 / 64, BATCH / 64), 256, 0, stream>>>(buf1, w_fc1, b_fc1, buf2, BATCH, 256, 1024);
    muls_kernel<<<(BATCH * 40) / 256, 256, 0, stream>>>(buf2, w_mu, b_mu, w_ls, b_ls, mu_out, ls_out);
    rev_kernel<<<(BATCH * 20) / 256, 256, 0, stream>>>(mu_out, ls_out, eps, zlat);
    fc2_kernel<<<BATCH, 256, 0, stream>>>(zlat, w_fc2, b_fc2, buf2);
    gemm_nt<true><<<dim3(1024 / 64, BATCH / 64), 256, 0, stream>>>(buf2, w_fc3, b_fc3, buf1, BATCH, 1024, 256);
    dec_kernel<<<BATCH, 256, 0, stream>>>(buf1, wtd1, b_d1, wtd2, b_d2, wtd3, b_d3, x_hat);
}

// Round 5
// 787.705 us; speedup vs baseline: 3.8161x; 1.0454x over previous
//
#include <hip/hip_runtime.h>
#include <math.h>

#define BATCH 4096

__device__ __forceinline__ void dot4a(float& acc, const float4 v, const float4 wt) {
    acc = fmaf(v.x, wt.x, acc);
    acc = fmaf(v.y, wt.y, acc);
    acc = fmaf(v.z, wt.z, acc);
    acc = fmaf(v.w, wt.w, acc);
}

// ======================= weight transpose pre-pass =======================
// All conv/deconv weights -> [co][tap][ci] (ci contiguous, float4-loadable).
__global__ __launch_bounds__(256) void tr_kernel(
    const float* __restrict__ w_c2, const float* __restrict__ w_c3,
    const float* __restrict__ w_d1, const float* __restrict__ w_d2,
    const float* __restrict__ w_d3,
    float* __restrict__ wt2, float* __restrict__ wt3,
    float* __restrict__ wtd1, float* __restrict__ wtd2, float* __restrict__ wtd3)
{
    int i = blockIdx.x * 256 + threadIdx.x;
    if (i < 16384) {  // w_c2 [32][32][16] -> wt2[(co*16+tap)*32+ci]
        int ci = i & 31, tap = (i >> 5) & 15, co = i >> 9;
        wt2[i] = w_c2[(co * 32 + ci) * 16 + tap];
    }
    if (i < 18432) {  // w_c3 [64][32][9] -> wt3[(co*9+tap)*32+ci]
        int ci = i & 31, r = i >> 5, tap = r % 9, co = r / 9;
        wt3[i] = w_c3[(co * 32 + ci) * 9 + tap];
    }
    if (i < 18432) {  // w_d1 [64][32][9] -> wtd1[(co*9+tap)*64+ci]
        int ci = i & 63, r = i >> 6, tap = r % 9, co = r / 9;
        wtd1[i] = w_d1[(ci * 32 + co) * 9 + tap];
    }
    if (i < 16384) {  // w_d2 [32][32][16] -> wtd2[(co*16+tap)*32+ci]
        int ci = i & 31, tap = (i >> 5) & 15, co = i >> 9;
        wtd2[i] = w_d2[(ci * 32 + co) * 16 + tap];
    }
    if (i < 512) {    // w_d3 [32][1][16] -> wtd3[tap*32+ci]
        int ci = i & 31, tap = i >> 5;
        wtd3[i] = w_d3[ci * 16 + tap];
    }
}

// ======================= fused encoder =======================
// 2 co per lane (8 FMA per b128 read); spatially padded LDS images so every
// tap read is base + constant immediate offset (no boundary masks).
__global__ __launch_bounds__(256, 3) void enc_kernel(
    const float* __restrict__ x,
    const float* __restrict__ w_c1, const float* __restrict__ b_c1,
    const float* __restrict__ wt2, const float* __restrict__ b_c2,
    const float* __restrict__ wt3, const float* __restrict__ b_c3,
    float* __restrict__ h3out)
{
    __shared__ __align__(16) float buf[12708];
    float* s_h1 = buf;            // padded 16x16 rows x 36  (h1: 14x14x32)
    float* s_h3 = buf;            // [1024] aliases h1 after conv2
    float* s_x  = buf + 9216;     // padded 30x30            (x: 28x28)
    float* s_h2 = buf + 10116;    // padded 9x9 rows x 32    (h2: 7x7x32)

    const int n = blockIdx.x, tid = threadIdx.x;
    const int wv = __builtin_amdgcn_readfirstlane((int)(tid >> 6));
    const int lane = tid & 63;
    const int co0 = wv * 8;

    // ---- zero padded regions, stage x interior ----
    {
        float4* z1 = (float4*)buf;
        #pragma unroll
        for (int i = tid; i < 2304; i += 256) z1[i] = make_float4(0.f, 0.f, 0.f, 0.f);
        float4* z2 = (float4*)(buf + 10116);
        for (int i = tid; i < 648; i += 256) z2[i] = make_float4(0.f, 0.f, 0.f, 0.f);
        for (int i = tid; i < 30; i += 256) { s_x[i] = 0.f; s_x[870 + i] = 0.f; }
        for (int i = tid; i < 28; i += 256) { s_x[(i + 1) * 30] = 0.f; s_x[(i + 1) * 30 + 29] = 0.f; }
        for (int i = tid; i < 784; i += 256) {
            int iy = i / 28, ix = i - iy * 28;
            s_x[(iy + 1) * 30 + ix + 1] = x[(size_t)n * 784 + i];
        }
    }
    __syncthreads();

    // ---- conv1: 1->32, k4 s2 p1, 28x28 -> 14x14, relu ----
    // lane = pos_off(4b) | pair(2b). 2 co per lane.
    {
        const int poff = lane & 15, pr = lane >> 4;
        const int ca = co0 + pr * 2;
        float w1a[16], w1b[16];
        #pragma unroll
        for (int k = 0; k < 4; ++k) {
            *(float4*)&w1a[4 * k] = *(const float4*)(w_c1 + ca * 16 + 4 * k);
            *(float4*)&w1b[4 * k] = *(const float4*)(w_c1 + (ca + 1) * 16 + 4 * k);
        }
        const float ba = b_c1[ca], bb = b_c1[ca + 1];
        for (int t = 0; t < 13; ++t) {
            int pos = poff + 16 * t;
            bool val = pos < 196;
            int p = val ? pos : 0;
            int oy = p / 14, ox = p - oy * 14;
            const float* bp = s_x + (2 * oy) * 30 + 2 * ox;
            float a0 = ba, a1 = bb;
            #pragma unroll
            for (int ky = 0; ky < 4; ++ky)
                #pragma unroll
                for (int kx = 0; kx < 4; ++kx) {
                    float v = bp[ky * 30 + kx];
                    a0 = fmaf(v, w1a[ky * 4 + kx], a0);
                    a1 = fmaf(v, w1b[ky * 4 + kx], a1);
                }
            if (val)
                *(float2*)(s_h1 + ((oy + 1) * 16 + ox + 1) * 36 + ca) =
                    make_float2(fmaxf(a0, 0.f), fmaxf(a1, 0.f));
        }
    }
    __syncthreads();

    // ---- conv2: 32->32, k4 s2 p1, 14x14 -> 7x7, relu ----
    // lane = parity(1b) | pair(2b) | cig(3b). 2 co x 4 ci per lane; butterfly over cig.
    {
        const int parity = lane & 1, pr = (lane >> 1) & 3, cig = lane >> 3;
        const int ca = co0 + pr * 2;
        float4 w2a[16], w2b[16];
        #pragma unroll
        for (int t = 0; t < 16; ++t) {
            w2a[t] = *(const float4*)(wt2 + (ca * 16 + t) * 32 + cig * 4);
            w2b[t] = *(const float4*)(wt2 + ((ca + 1) * 16 + t) * 32 + cig * 4);
        }
        const float ba = b_c2[ca], bb = b_c2[ca + 1];
        for (int t = 0; t < 25; ++t) {
            int pos = parity + 2 * t;
            bool val = pos < 49;
            int p = val ? pos : 0;
            int oy = p / 7, ox = p - oy * 7;
            const float* bp = s_h1 + ((2 * oy) * 16 + 2 * ox) * 36 + cig * 4;
            float a0 = 0.f, a1 = 0.f;
            #pragma unroll
            for (int ky = 0; ky < 4; ++ky)
                #pragma unroll
                for (int kx = 0; kx < 4; ++kx) {
                    float4 v = *(const float4*)(bp + (ky * 16 + kx) * 36);
                    dot4a(a0, v, w2a[ky * 4 + kx]);
                    dot4a(a1, v, w2b[ky * 4 + kx]);
                }
            a0 += __shfl_xor(a0, 8);  a1 += __shfl_xor(a1, 8);
            a0 += __shfl_xor(a0, 16); a1 += __shfl_xor(a1, 16);
            a0 += __shfl_xor(a0, 32); a1 += __shfl_xor(a1, 32);
            if (cig == 0 && val)
                *(float2*)(s_h2 + ((oy + 1) * 9 + ox + 1) * 32 + ca) =
                    make_float2(fmaxf(a0 + ba, 0.f), fmaxf(a1 + bb, 0.f));
        }
    }
    __syncthreads();

    // ---- conv3: 32->64, k3 s2 p1, 7x7 -> 4x4, relu ----
    // lane = pair(3b) | cig(3b). wave owns 16 co; 2 co x 4 ci per lane.
    {
        const int pr = lane & 7, cig = lane >> 3;
        const int ca = wv * 16 + pr * 2;
        float4 w3a[9], w3b[9];
        #pragma unroll
        for (int t = 0; t < 9; ++t) {
            w3a[t] = *(const float4*)(wt3 + (ca * 9 + t) * 32 + cig * 4);
            w3b[t] = *(const float4*)(wt3 + ((ca + 1) * 9 + t) * 32 + cig * 4);
        }
        const float ba = b_c3[ca], bb = b_c3[ca + 1];
        #pragma unroll 2
        for (int pos = 0; pos < 16; ++pos) {
            int oy = pos >> 2, ox = pos & 3;
            const float* bp = s_h2 + ((2 * oy) * 9 + 2 * ox) * 32 + cig * 4;
            float a0 = 0.f, a1 = 0.f;
            #pragma unroll
            for (int ky = 0; ky < 3; ++ky)
                #pragma unroll
                for (int kx = 0; kx < 3; ++kx) {
                    float4 v = *(const float4*)(bp + (ky * 9 + kx) * 32);
                    dot4a(a0, v, w3a[ky * 3 + kx]);
                    dot4a(a1, v, w3b[ky * 3 + kx]);
                }
            a0 += __shfl_xor(a0, 8);  a1 += __shfl_xor(a1, 8);
            a0 += __shfl_xor(a0, 16); a1 += __shfl_xor(a1, 16);
            a0 += __shfl_xor(a0, 32); a1 += __shfl_xor(a1, 32);
            if (cig == 0) {
                s_h3[ca * 16 + pos] = fmaxf(a0 + ba, 0.f);
                s_h3[(ca + 1) * 16 + pos] = fmaxf(a1 + bb, 0.f);
            }
        }
    }
    __syncthreads();
    for (int i = tid; i < 1024; i += 256) h3out[(size_t)n * 1024 + i] = s_h3[i];
}

// ======================= tiled NT SGEMM =======================
template <bool RELU>
__global__ __launch_bounds__(256) void gemm_nt(
    const float* __restrict__ A, const float* __restrict__ W,
    const float* __restrict__ bias, float* __restrict__ C,
    int M, int N, int K)
{
    __shared__ float As[16][65];
    __shared__ float Ws[16][65];
    const int tid = threadIdx.x;
    const int col0 = blockIdx.x * 64;
    const int row0 = blockIdx.y * 64;
    const int tx = tid & 15, ty = tid >> 4;
    const int lr = tid >> 2, lc = (tid & 3) * 4;
    float acc[4][4] = {};

    for (int k0 = 0; k0 < K; k0 += 16) {
        float4 av = *(const float4*)(A + (size_t)(row0 + lr) * K + k0 + lc);
        float4 wv = *(const float4*)(W + (size_t)(col0 + lr) * K + k0 + lc);
        As[lc + 0][lr] = av.x; As[lc + 1][lr] = av.y; As[lc + 2][lr] = av.z; As[lc + 3][lr] = av.w;
        Ws[lc + 0][lr] = wv.x; Ws[lc + 1][lr] = wv.y; Ws[lc + 2][lr] = wv.z; Ws[lc + 3][lr] = wv.w;
        __syncthreads();
        #pragma unroll
        for (int kk = 0; kk < 16; ++kk) {
            float a[4], b[4];
            #pragma unroll
            for (int i = 0; i < 4; ++i) a[i] = As[kk][ty * 4 + i];
            #pragma unroll
            for (int j = 0; j < 4; ++j) b[j] = Ws[kk][tx * 4 + j];
            #pragma unroll
            for (int i = 0; i < 4; ++i)
                #pragma unroll
                for (int j = 0; j < 4; ++j)
                    acc[i][j] = fmaf(a[i], b[j], acc[i][j]);
        }
        __syncthreads();
    }
    #pragma unroll
    for (int i = 0; i < 4; ++i) {
        int row = row0 + ty * 4 + i;
        float* cp = C + (size_t)row * N + col0 + tx * 4;
        float4 v;
        v.x = acc[i][0] + bias[col0 + tx * 4 + 0];
        v.y = acc[i][1] + bias[col0 + tx * 4 + 1];
        v.z = acc[i][2] + bias[col0 + tx * 4 + 2];
        v.w = acc[i][3] + bias[col0 + tx * 4 + 3];
        if (RELU) {
            v.x = fmaxf(v.x, 0.f); v.y = fmaxf(v.y, 0.f);
            v.z = fmaxf(v.z, 0.f); v.w = fmaxf(v.w, 0.f);
        }
        *(float4*)cp = v;
    }
}

// ======================= mu / logvar heads =======================
__global__ __launch_bounds__(256) void muls_kernel(
    const float* __restrict__ h,
    const float* __restrict__ w_mu, const float* __restrict__ b_mu,
    const float* __restrict__ w_ls, const float* __restrict__ b_ls,
    float* __restrict__ mu_out, float* __restrict__ ls_out)
{
    int idx = blockIdx.x * 256 + threadIdx.x;
    if (idx >= BATCH * 40) return;
    int i = idx / 40, j = idx % 40;
    bool is_mu = j < 20;
    int jj = is_mu ? j : j - 20;
    const float* wrow = is_mu ? (w_mu + jj * 256) : (w_ls + jj * 256);
    float acc = is_mu ? b_mu[jj] : b_ls[jj];
    const float4* hp = (const float4*)(h + (size_t)i * 256);
    const float4* wp = (const float4*)wrow;
    #pragma unroll 8
    for (int k = 0; k < 64; ++k) {
        float4 hv = hp[k], wv = wp[k];
        acc = fmaf(hv.x, wv.x, acc);
        acc = fmaf(hv.y, wv.y, acc);
        acc = fmaf(hv.z, wv.z, acc);
        acc = fmaf(hv.w, wv.w, acc);
    }
    (is_mu ? mu_out : ls_out)[i * 20 + jj] = acc;
}

// ======================= 100-step reversing + reparameterize =======================
__global__ __launch_bounds__(256) void rev_kernel(
    const float* __restrict__ mu, const float* __restrict__ ls,
    const float* __restrict__ eps, float* __restrict__ z)
{
    int idx = blockIdx.x * 256 + threadIdx.x;
    if (idx >= BATCH * 20) return;
    double m = (double)mu[idx];
    double s = (double)ls[idx];
    #pragma unroll 4
    for (int t = 0; t < 100; ++t) {
        m += 0.1 * m;
        s += 0.05 * (exp(s) - 1.0);
    }
    z[idx] = (float)((double)eps[idx] * exp(0.5 * s) + m);
}

// ======================= fc2: [B,20] -> [B,256], relu =======================
__global__ __launch_bounds__(256) void fc2_kernel(
    const float* __restrict__ z, const float* __restrict__ w, const float* __restrict__ b,
    float* __restrict__ out)
{
    int idx = blockIdx.x * 256 + threadIdx.x;
    int i = idx >> 8, j = idx & 255;
    float acc = b[j];
    const float* zp = z + i * 20;
    const float* wp = w + j * 20;
    #pragma unroll
    for (int k = 0; k < 20; ++k) acc = fmaf(zp[k], wp[k], acc);
    out[idx] = fmaxf(acc, 0.f);
}

// ======================= fused decoder =======================
__global__ __launch_bounds__(256, 3) void dec_kernel(
    const float* __restrict__ hin,
    const float* __restrict__ wtd1, const float* __restrict__ b_d1,
    const float* __restrict__ wtd2, const float* __restrict__ b_d2,
    const float* __restrict__ wtd3, const float* __restrict__ b_d3,
    float* __restrict__ xhat)
{
    __shared__ __align__(16) float dbuf[12896];
    float* s_d2   = dbuf;            // padded 16x16 rows x 36 (d2: 14x14x32)
    float* s_d1   = dbuf + 9216;     // padded 9x9 rows x 32   (d1: 7x7x32)
    float* s_in   = dbuf + 11808;    // [16 pos][68]
    float* s_part = dbuf + 11808;    // [4][196] aliases s_in after deconv1

    const int n = blockIdx.x, tid = threadIdx.x;
    const int wv = __builtin_amdgcn_readfirstlane((int)(tid >> 6));
    const int lane = tid & 63;
    const int co0 = wv * 8;

    {
        float4* z1 = (float4*)dbuf;
        #pragma unroll
        for (int i = tid; i < 2952; i += 256) z1[i] = make_float4(0.f, 0.f, 0.f, 0.f);
        for (int t = tid; t < 1024; t += 256) {
            int c = t & 63, p = t >> 6;
            s_in[p * 68 + c] = hin[(size_t)n * 1024 + c * 16 + p];
        }
    }
    __syncthreads();

    // ---- deconv1: ConvT 64->32 k3 s2 p1, 4x4 -> 7x7, relu ----
    // lane = pair(2b) | cig(4b, 16 groups of 4 ci). 2 co x 4 ci; butterfly over cig.
    {
        const int pr = lane & 3, cig = lane >> 2;
        const int ca = co0 + pr * 2;
        float4 wa[9], wb[9];
        #pragma unroll
        for (int t = 0; t < 9; ++t) {
            wa[t] = *(const float4*)(wtd1 + (ca * 9 + t) * 64 + cig * 4);
            wb[t] = *(const float4*)(wtd1 + ((ca + 1) * 9 + t) * 64 + cig * 4);
        }
        const float ba = b_d1[ca], bb = b_d1[ca + 1];
        #pragma unroll
        for (int py = 0; py < 2; ++py) {
            #pragma unroll
            for (int px = 0; px < 2; ++px) {
                const int ny = 4 - py, nx = 4 - px;
                for (int sy = 0; sy < ny; ++sy) {
                    for (int sx = 0; sx < nx; ++sx) {
                        float a0 = 0.f, a1 = 0.f;
                        #pragma unroll
                        for (int a = 0; a <= 1; ++a) {
                            if (a == 1 && py == 0) continue;
                            int ky = py ? (a ? 2 : 0) : 1;
                            int iy = py ? (a ? sy : sy + 1) : sy;
                            #pragma unroll
                            for (int b = 0; b <= 1; ++b) {
                                if (b == 1 && px == 0) continue;
                                int kx = px ? (b ? 2 : 0) : 1;
                                int ix = px ? (b ? sx : sx + 1) : sx;
                                float4 v = *(const float4*)(s_in + (iy * 4 + ix) * 68 + cig * 4);
                                int tp = ky * 3 + kx;
                                dot4a(a0, v, wa[tp]);
                                dot4a(a1, v, wb[tp]);
                            }
                        }
                        a0 += __shfl_xor(a0, 4);  a1 += __shfl_xor(a1, 4);
                        a0 += __shfl_xor(a0, 8);  a1 += __shfl_xor(a1, 8);
                        a0 += __shfl_xor(a0, 16); a1 += __shfl_xor(a1, 16);
                        a0 += __shfl_xor(a0, 32); a1 += __shfl_xor(a1, 32);
                        if (cig == 0) {
                            int oy = 2 * sy + py, ox = 2 * sx + px;
                            *(float2*)(s_d1 + ((oy + 1) * 9 + ox + 1) * 32 + ca) =
                                make_float2(fmaxf(a0 + ba, 0.f), fmaxf(a1 + bb, 0.f));
                        }
                    }
                }
            }
        }
    }
    __syncthreads();

    // ---- deconv2: ConvT 32->32 k4 s2 p1, 7x7 -> 14x14, relu ----
    // lane = soff(1b) | pair(2b) | cig(3b). 2 co x 4 ci; padded d1 (no masks).
    {
        const int soff = lane & 1, pr = (lane >> 1) & 3, cig = lane >> 3;
        const int ca = co0 + pr * 2;
        float4 wa[16], wb[16];
        #pragma unroll
        for (int t = 0; t < 16; ++t) {
            wa[t] = *(const float4*)(wtd2 + (ca * 16 + t) * 32 + cig * 4);
            wb[t] = *(const float4*)(wtd2 + ((ca + 1) * 16 + t) * 32 + cig * 4);
        }
        const float ba = b_d2[ca], bb = b_d2[ca + 1];
        for (int t = 0; t < 25; ++t) {
            int spos = soff + 2 * t;
            bool val = spos < 49;
            int sp = val ? spos : 0;
            int sy = sp / 7, sx = sp - sy * 7;
            const float* bp = s_d1 + (sy * 9 + sx) * 32 + cig * 4;  // corner (dy=-1,dx=-1)
            #pragma unroll
            for (int py = 0; py < 2; ++py) {
                float4 va[2][3];
                #pragma unroll
                for (int l = 0; l < 2; ++l)
                    #pragma unroll
                    for (int b = 0; b < 3; ++b)
                        va[l][b] = *(const float4*)(bp + ((l + py) * 9 + b) * 32);
                #pragma unroll
                for (int px = 0; px < 2; ++px) {
                    float a0 = 0.f, a1 = 0.f;
                    #pragma unroll
                    for (int a2 = 0; a2 < 2; ++a2) {
                        int ky = py ? (a2 ? 2 : 0) : (a2 ? 3 : 1);
                        int l = 1 - a2;
                        #pragma unroll
                        for (int b2 = 0; b2 < 2; ++b2) {
                            int kx = px ? (b2 ? 2 : 0) : (b2 ? 3 : 1);
                            int m = px ? (2 - b2) : (1 - b2);  // dx+1: px=0 -> {1,0}; px=1 -> {2,1}
                            int tp = ky * 4 + kx;
                            float4 v = va[l][m];
                            dot4a(a0, v, wa[tp]);
                            dot4a(a1, v, wb[tp]);
                        }
                    }
                    a0 += __shfl_xor(a0, 8);  a1 += __shfl_xor(a1, 8);
                    a0 += __shfl_xor(a0, 16); a1 += __shfl_xor(a1, 16);
                    a0 += __shfl_xor(a0, 32); a1 += __shfl_xor(a1, 32);
                    if (cig == 0 && val) {
                        int oy = 2 * sy + py, ox = 2 * sx + px;
                        *(float2*)(s_d2 + ((oy + 1) * 16 + ox + 1) * 36 + ca) =
                            make_float2(fmaxf(a0 + ba, 0.f), fmaxf(a1 + bb, 0.f));
                    }
                }
            }
        }
    }
    __syncthreads();

    // ---- deconv3: ConvT 32->1 k4 s2 p1, 14x14 -> 28x28, sigmoid ----
    // wave wv owns ci [wv*8, wv*8+8); lane = spos chunk; padded d2 (no masks).
    {
        const int ci0 = wv * 8;
        const float bd3 = b_d3[0];
        #pragma unroll
        for (int py = 0; py < 2; ++py) {
            #pragma unroll
            for (int px = 0; px < 2; ++px) {
                float w3r[2][2][8];
                #pragma unroll
                for (int a = 0; a < 2; ++a) {
                    int ky = py ? (a ? 2 : 0) : (a ? 3 : 1);
                    #pragma unroll
                    for (int b = 0; b < 2; ++b) {
                        int kx = px ? (b ? 2 : 0) : (b ? 3 : 1);
                        *(float4*)(w3r[a][b])     = *(const float4*)(wtd3 + (ky * 4 + kx) * 32 + ci0);
                        *(float4*)(w3r[a][b] + 4) = *(const float4*)(wtd3 + (ky * 4 + kx) * 32 + ci0 + 4);
                    }
                }
                for (int t = 0; t < 4; ++t) {
                    int spos = t * 64 + lane;
                    bool val = spos < 196;
                    int sp = val ? spos : 0;
                    int sy = sp / 14, sx = sp - sy * 14;
                    const float* bp = s_d2 + ((sy + py) * 16 + sx + px) * 36 + ci0;  // (a=1,b=1) corner
                    float acc = 0.f;
                    #pragma unroll
                    for (int a = 0; a < 2; ++a) {
                        #pragma unroll
                        for (int b = 0; b < 2; ++b) {
                            const float* vp = bp + ((1 - a) * 16 + (1 - b)) * 36;
                            float4 v0 = *(const float4*)(vp);
                            float4 v1 = *(const float4*)(vp + 4);
                            acc = fmaf(v0.x, w3r[a][b][0], acc);
                            acc = fmaf(v0.y, w3r[a][b][1], acc);
                            acc = fmaf(v0.z, w3r[a][b][2], acc);
                            acc = fmaf(v0.w, w3r[a][b][3], acc);
                            acc = fmaf(v1.x, w3r[a][b][4], acc);
                            acc = fmaf(v1.y, w3r[a][b][5], acc);
                            acc = fmaf(v1.z, w3r[a][b][6], acc);
                            acc = fmaf(v1.w, w3r[a][b][7], acc);
                        }
                    }
                    if (val) s_part[wv * 196 + sp] = acc;
                }
                __syncthreads();
                if (tid < 196) {
                    float s = s_part[tid] + s_part[196 + tid] + s_part[392 + tid] + s_part[588 + tid];
                    int sy = tid / 14, sx = tid - sy * 14;
                    xhat[(size_t)n * 784 + (2 * sy + py) * 28 + 2 * sx + px] =
                        1.f / (1.f + expf(-(s + bd3)));
                }
                __syncthreads();
            }
        }
    }
}

extern "C" void kernel_launch(void* const* d_in, const int* in_sizes, int n_in,
                              void* d_out, int out_size, void* d_ws, size_t ws_size,
                              hipStream_t stream) {
    const float* x     = (const float*)d_in[0];
    const float* eps   = (const float*)d_in[1];
    const float* w_c1  = (const float*)d_in[2];
    const float* b_c1  = (const float*)d_in[3];
    const float* w_c2  = (const float*)d_in[4];
    const float* b_c2  = (const float*)d_in[5];
    const float* w_c3  = (const float*)d_in[6];
    const float* b_c3  = (const float*)d_in[7];
    const float* w_fc1 = (const float*)d_in[8];
    const float* b_fc1 = (const float*)d_in[9];
    const float* w_mu  = (const float*)d_in[10];
    const float* b_mu  = (const float*)d_in[11];
    const float* w_ls  = (const float*)d_in[12];
    const float* b_ls  = (const float*)d_in[13];
    const float* w_fc2 = (const float*)d_in[14];
    const float* b_fc2 = (const float*)d_in[15];
    const float* w_fc3 = (const float*)d_in[16];
    const float* b_fc3 = (const float*)d_in[17];
    const float* w_d1  = (const float*)d_in[18];
    const float* b_d1  = (const float*)d_in[19];
    const float* w_d2  = (const float*)d_in[20];
    const float* b_d2  = (const float*)d_in[21];
    const float* w_d3  = (const float*)d_in[22];
    const float* b_d3  = (const float*)d_in[23];

    float* out = (float*)d_out;
    float* x_hat  = out;                  // 4096*784
    float* mu_out = out + 4096 * 784;     // 4096*20
    float* ls_out = mu_out + 4096 * 20;   // 4096*20

    float* buf1 = (float*)d_ws;           // 4096*1024 (h3 / fc3 out); zlat reuses head
    float* buf2 = buf1 + 4096 * 1024;     // 4096*256  (fc1 out / fc2 out)
    float* zlat = buf1;                   // 4096*20, live only between rev and fc2
    float* wt2  = buf2 + 4096 * 256;      // 16384
    float* wt3  = wt2 + 16384;            // 18432
    float* wtd1 = wt3 + 18432;            // 18432
    float* wtd2 = wtd1 + 18432;           // 16384
    float* wtd3 = wtd2 + 16384;           // 512

    tr_kernel<<<72, 256, 0, stream>>>(w_c2, w_c3, w_d1, w_d2, w_d3, wt2, wt3, wtd1, wtd2, wtd3);
    enc_kernel<<<BATCH, 256, 0, stream>>>(x, w_c1, b_c1, wt2, b_c2, wt3, b_c3, buf1);
    gemm_nt<true><<<dim3(256 / 64, BATCH / 64), 256, 0, stream>>>(buf1, w_fc1, b_fc1, buf2, BATCH, 256, 1024);
    muls_kernel<<<(BATCH * 40) / 256, 256, 0, stream>>>(buf2, w_mu, b_mu, w_ls, b_ls, mu_out, ls_out);
    rev_kernel<<<(BATCH * 20) / 256, 256, 0, stream>>>(mu_out, ls_out, eps, zlat);
    fc2_kernel<<<BATCH, 256, 0, stream>>>(zlat, w_fc2, b_fc2, buf2);
    gemm_nt<true><<<dim3(1024 / 64, BATCH / 64), 256, 0, stream>>>(buf2, w_fc3, b_fc3, buf1, BATCH, 1024, 256);
    dec_kernel<<<BATCH, 256, 0, stream>>>(buf1, wtd1, b_d1, wtd2, b_d2, wtd3, b_d3, x_hat);
}

// Round 6
// 648.796 us; speedup vs baseline: 4.6332x; 1.2141x over previous
//
#include <hip/hip_runtime.h>
#include <math.h>

#define BATCH 4096

__device__ __forceinline__ void dot4a(float& acc, const float4 v, const float4 wt) {
    acc = fmaf(v.x, wt.x, acc);
    acc = fmaf(v.y, wt.y, acc);
    acc = fmaf(v.z, wt.z, acc);
    acc = fmaf(v.w, wt.w, acc);
}

// ======================= weight transpose pre-pass =======================
// All conv/deconv weights -> [co][tap][ci] (ci contiguous, float4-loadable).
__global__ __launch_bounds__(256) void tr_kernel(
    const float* __restrict__ w_c2, const float* __restrict__ w_c3,
    const float* __restrict__ w_d1, const float* __restrict__ w_d2,
    const float* __restrict__ w_d3,
    float* __restrict__ wt2, float* __restrict__ wt3,
    float* __restrict__ wtd1, float* __restrict__ wtd2, float* __restrict__ wtd3)
{
    int i = blockIdx.x * 256 + threadIdx.x;
    if (i < 16384) {  // w_c2 [32][32][16] -> wt2[(co*16+tap)*32+ci]
        int ci = i & 31, tap = (i >> 5) & 15, co = i >> 9;
        wt2[i] = w_c2[(co * 32 + ci) * 16 + tap];
    }
    if (i < 18432) {  // w_c3 [64][32][9] -> wt3[(co*9+tap)*32+ci]
        int ci = i & 31, r = i >> 5, tap = r % 9, co = r / 9;
        wt3[i] = w_c3[(co * 32 + ci) * 9 + tap];
    }
    if (i < 18432) {  // w_d1 [64][32][9] -> wtd1[(co*9+tap)*64+ci]
        int ci = i & 63, r = i >> 6, tap = r % 9, co = r / 9;
        wtd1[i] = w_d1[(ci * 32 + co) * 9 + tap];
    }
    if (i < 16384) {  // w_d2 [32][32][16] -> wtd2[(co*16+tap)*32+ci]
        int ci = i & 31, tap = (i >> 5) & 15, co = i >> 9;
        wtd2[i] = w_d2[(ci * 32 + co) * 16 + tap];
    }
    if (i < 512) {    // w_d3 [32][1][16] -> wtd3[tap*32+ci]
        int ci = i & 31, tap = i >> 5;
        wtd3[i] = w_d3[ci * 16 + tap];
    }
}

// ======================= fused encoder (unchanged from R5) =======================
__global__ __launch_bounds__(256, 3) void enc_kernel(
    const float* __restrict__ x,
    const float* __restrict__ w_c1, const float* __restrict__ b_c1,
    const float* __restrict__ wt2, const float* __restrict__ b_c2,
    const float* __restrict__ wt3, const float* __restrict__ b_c3,
    float* __restrict__ h3out)
{
    __shared__ __align__(16) float buf[12708];
    float* s_h1 = buf;            // padded 16x16 rows x 36  (h1: 14x14x32)
    float* s_h3 = buf;            // [1024] aliases h1 after conv2
    float* s_x  = buf + 9216;     // padded 30x30            (x: 28x28)
    float* s_h2 = buf + 10116;    // padded 9x9 rows x 32    (h2: 7x7x32)

    const int n = blockIdx.x, tid = threadIdx.x;
    const int wv = __builtin_amdgcn_readfirstlane((int)(tid >> 6));
    const int lane = tid & 63;
    const int co0 = wv * 8;

    {
        float4* z1 = (float4*)buf;
        #pragma unroll
        for (int i = tid; i < 2304; i += 256) z1[i] = make_float4(0.f, 0.f, 0.f, 0.f);
        float4* z2 = (float4*)(buf + 10116);
        for (int i = tid; i < 648; i += 256) z2[i] = make_float4(0.f, 0.f, 0.f, 0.f);
        for (int i = tid; i < 30; i += 256) { s_x[i] = 0.f; s_x[870 + i] = 0.f; }
        for (int i = tid; i < 28; i += 256) { s_x[(i + 1) * 30] = 0.f; s_x[(i + 1) * 30 + 29] = 0.f; }
        for (int i = tid; i < 784; i += 256) {
            int iy = i / 28, ix = i - iy * 28;
            s_x[(iy + 1) * 30 + ix + 1] = x[(size_t)n * 784 + i];
        }
    }
    __syncthreads();

    // ---- conv1 ----
    {
        const int poff = lane & 15, pr = lane >> 4;
        const int ca = co0 + pr * 2;
        float w1a[16], w1b[16];
        #pragma unroll
        for (int k = 0; k < 4; ++k) {
            *(float4*)&w1a[4 * k] = *(const float4*)(w_c1 + ca * 16 + 4 * k);
            *(float4*)&w1b[4 * k] = *(const float4*)(w_c1 + (ca + 1) * 16 + 4 * k);
        }
        const float ba = b_c1[ca], bb = b_c1[ca + 1];
        for (int t = 0; t < 13; ++t) {
            int pos = poff + 16 * t;
            bool val = pos < 196;
            int p = val ? pos : 0;
            int oy = p / 14, ox = p - oy * 14;
            const float* bp = s_x + (2 * oy) * 30 + 2 * ox;
            float a0 = ba, a1 = bb;
            #pragma unroll
            for (int ky = 0; ky < 4; ++ky)
                #pragma unroll
                for (int kx = 0; kx < 4; ++kx) {
                    float v = bp[ky * 30 + kx];
                    a0 = fmaf(v, w1a[ky * 4 + kx], a0);
                    a1 = fmaf(v, w1b[ky * 4 + kx], a1);
                }
            if (val)
                *(float2*)(s_h1 + ((oy + 1) * 16 + ox + 1) * 36 + ca) =
                    make_float2(fmaxf(a0, 0.f), fmaxf(a1, 0.f));
        }
    }
    __syncthreads();

    // ---- conv2 ----
    {
        const int parity = lane & 1, pr = (lane >> 1) & 3, cig = lane >> 3;
        const int ca = co0 + pr * 2;
        float4 w2a[16], w2b[16];
        #pragma unroll
        for (int t = 0; t < 16; ++t) {
            w2a[t] = *(const float4*)(wt2 + (ca * 16 + t) * 32 + cig * 4);
            w2b[t] = *(const float4*)(wt2 + ((ca + 1) * 16 + t) * 32 + cig * 4);
        }
        const float ba = b_c2[ca], bb = b_c2[ca + 1];
        for (int t = 0; t < 25; ++t) {
            int pos = parity + 2 * t;
            bool val = pos < 49;
            int p = val ? pos : 0;
            int oy = p / 7, ox = p - oy * 7;
            const float* bp = s_h1 + ((2 * oy) * 16 + 2 * ox) * 36 + cig * 4;
            float a0 = 0.f, a1 = 0.f;
            #pragma unroll
            for (int ky = 0; ky < 4; ++ky)
                #pragma unroll
                for (int kx = 0; kx < 4; ++kx) {
                    float4 v = *(const float4*)(bp + (ky * 16 + kx) * 36);
                    dot4a(a0, v, w2a[ky * 4 + kx]);
                    dot4a(a1, v, w2b[ky * 4 + kx]);
                }
            a0 += __shfl_xor(a0, 8);  a1 += __shfl_xor(a1, 8);
            a0 += __shfl_xor(a0, 16); a1 += __shfl_xor(a1, 16);
            a0 += __shfl_xor(a0, 32); a1 += __shfl_xor(a1, 32);
            if (cig == 0 && val)
                *(float2*)(s_h2 + ((oy + 1) * 9 + ox + 1) * 32 + ca) =
                    make_float2(fmaxf(a0 + ba, 0.f), fmaxf(a1 + bb, 0.f));
        }
    }
    __syncthreads();

    // ---- conv3 ----
    {
        const int pr = lane & 7, cig = lane >> 3;
        const int ca = wv * 16 + pr * 2;
        float4 w3a[9], w3b[9];
        #pragma unroll
        for (int t = 0; t < 9; ++t) {
            w3a[t] = *(const float4*)(wt3 + (ca * 9 + t) * 32 + cig * 4);
            w3b[t] = *(const float4*)(wt3 + ((ca + 1) * 9 + t) * 32 + cig * 4);
        }
        const float ba = b_c3[ca], bb = b_c3[ca + 1];
        #pragma unroll 2
        for (int pos = 0; pos < 16; ++pos) {
            int oy = pos >> 2, ox = pos & 3;
            const float* bp = s_h2 + ((2 * oy) * 9 + 2 * ox) * 32 + cig * 4;
            float a0 = 0.f, a1 = 0.f;
            #pragma unroll
            for (int ky = 0; ky < 3; ++ky)
                #pragma unroll
                for (int kx = 0; kx < 3; ++kx) {
                    float4 v = *(const float4*)(bp + (ky * 9 + kx) * 32);
                    dot4a(a0, v, w3a[ky * 3 + kx]);
                    dot4a(a1, v, w3b[ky * 3 + kx]);
                }
            a0 += __shfl_xor(a0, 8);  a1 += __shfl_xor(a1, 8);
            a0 += __shfl_xor(a0, 16); a1 += __shfl_xor(a1, 16);
            a0 += __shfl_xor(a0, 32); a1 += __shfl_xor(a1, 32);
            if (cig == 0) {
                s_h3[ca * 16 + pos] = fmaxf(a0 + ba, 0.f);
                s_h3[(ca + 1) * 16 + pos] = fmaxf(a1 + bb, 0.f);
            }
        }
    }
    __syncthreads();
    for (int i = tid; i < 1024; i += 256) h3out[(size_t)n * 1024 + i] = s_h3[i];
}

// ======================= tiled NT SGEMM =======================
template <bool RELU>
__global__ __launch_bounds__(256) void gemm_nt(
    const float* __restrict__ A, const float* __restrict__ W,
    const float* __restrict__ bias, float* __restrict__ C,
    int M, int N, int K)
{
    __shared__ float As[16][65];
    __shared__ float Ws[16][65];
    const int tid = threadIdx.x;
    const int col0 = blockIdx.x * 64;
    const int row0 = blockIdx.y * 64;
    const int tx = tid & 15, ty = tid >> 4;
    const int lr = tid >> 2, lc = (tid & 3) * 4;
    float acc[4][4] = {};

    for (int k0 = 0; k0 < K; k0 += 16) {
        float4 av = *(const float4*)(A + (size_t)(row0 + lr) * K + k0 + lc);
        float4 wv = *(const float4*)(W + (size_t)(col0 + lr) * K + k0 + lc);
        As[lc + 0][lr] = av.x; As[lc + 1][lr] = av.y; As[lc + 2][lr] = av.z; As[lc + 3][lr] = av.w;
        Ws[lc + 0][lr] = wv.x; Ws[lc + 1][lr] = wv.y; Ws[lc + 2][lr] = wv.z; Ws[lc + 3][lr] = wv.w;
        __syncthreads();
        #pragma unroll
        for (int kk = 0; kk < 16; ++kk) {
            float a[4], b[4];
            #pragma unroll
            for (int i = 0; i < 4; ++i) a[i] = As[kk][ty * 4 + i];
            #pragma unroll
            for (int j = 0; j < 4; ++j) b[j] = Ws[kk][tx * 4 + j];
            #pragma unroll
            for (int i = 0; i < 4; ++i)
                #pragma unroll
                for (int j = 0; j < 4; ++j)
                    acc[i][j] = fmaf(a[i], b[j], acc[i][j]);
        }
        __syncthreads();
    }
    #pragma unroll
    for (int i = 0; i < 4; ++i) {
        int row = row0 + ty * 4 + i;
        float* cp = C + (size_t)row * N + col0 + tx * 4;
        float4 v;
        v.x = acc[i][0] + bias[col0 + tx * 4 + 0];
        v.y = acc[i][1] + bias[col0 + tx * 4 + 1];
        v.z = acc[i][2] + bias[col0 + tx * 4 + 2];
        v.w = acc[i][3] + bias[col0 + tx * 4 + 3];
        if (RELU) {
            v.x = fmaxf(v.x, 0.f); v.y = fmaxf(v.y, 0.f);
            v.z = fmaxf(v.z, 0.f); v.w = fmaxf(v.w, 0.f);
        }
        *(float4*)cp = v;
    }
}

// ======= fused mu/logvar heads + 100-step reversing + reparameterize =======
// m-path in double (cheap, exact); s-path fp32 (contraction keeps error ~1e-5).
__global__ __launch_bounds__(256) void mulsrev_kernel(
    const float* __restrict__ h,
    const float* __restrict__ w_mu, const float* __restrict__ b_mu,
    const float* __restrict__ w_ls, const float* __restrict__ b_ls,
    const float* __restrict__ eps,
    float* __restrict__ mu_out, float* __restrict__ ls_out, float* __restrict__ z)
{
    int idx = blockIdx.x * 256 + threadIdx.x;
    if (idx >= BATCH * 20) return;
    int i = idx / 20, j = idx - i * 20;
    const float4* hp = (const float4*)(h + (size_t)i * 256);
    const float4* mp = (const float4*)(w_mu + j * 256);
    const float4* lp = (const float4*)(w_ls + j * 256);
    float am = b_mu[j], al = b_ls[j];
    #pragma unroll 8
    for (int k = 0; k < 64; ++k) {
        float4 hv = hp[k], mv = mp[k], lv = lp[k];
        am = fmaf(hv.x, mv.x, am); al = fmaf(hv.x, lv.x, al);
        am = fmaf(hv.y, mv.y, am); al = fmaf(hv.y, lv.y, al);
        am = fmaf(hv.z, mv.z, am); al = fmaf(hv.z, lv.z, al);
        am = fmaf(hv.w, mv.w, am); al = fmaf(hv.w, lv.w, al);
    }
    mu_out[idx] = am;
    ls_out[idx] = al;
    double m = (double)am;
    float s = al;
    #pragma unroll 4
    for (int t = 0; t < 100; ++t) {
        m += 0.1 * m;
        s += 0.05f * (expf(s) - 1.f);
    }
    z[idx] = fmaf(eps[idx], expf(0.5f * s), (float)m);
}

// ======================= fc2: [B,20] -> [B,256], relu =======================
__global__ __launch_bounds__(256) void fc2_kernel(
    const float* __restrict__ z, const float* __restrict__ w, const float* __restrict__ b,
    float* __restrict__ out)
{
    int idx = blockIdx.x * 256 + threadIdx.x;
    int i = idx >> 8, j = idx & 255;
    float acc = b[j];
    const float* zp = z + i * 20;
    const float* wp = w + j * 20;
    #pragma unroll
    for (int k = 0; k < 20; ++k) acc = fmaf(zp[k], wp[k], acc);
    out[idx] = fmaxf(acc, 0.f);
}

// ======================= fused decoder (restructured) =======================
// deconv1/2: parity-class lanes, 4-co register tiles, shallow ci-butterflies.
// deconv3: P-matrix (P[t][pos] = sum_ci d2*w3) then masked 4-tap gather.
__global__ __launch_bounds__(256, 3) void dec_kernel(
    const float* __restrict__ hin,
    const float* __restrict__ wtd1, const float* __restrict__ b_d1,
    const float* __restrict__ wtd2, const float* __restrict__ b_d2,
    const float* __restrict__ wtd3, const float* __restrict__ b_d3,
    float* __restrict__ xhat)
{
    __shared__ __align__(16) float dbuf[11060];
    float* s_d2 = dbuf;            // [196 pos][36]  (d2: 14x14x32, no spatial pad)
    float* s_d1 = dbuf + 7056;     // padded 9x9 rows x 36 (d1: 7x7x32)
    float* s_in = dbuf + 9972;     // [16 pos][68]
    float* sP   = dbuf + 7056;     // P[16 taps][196 pos] aliases s_d1+s_in after deconv2

    const int n = blockIdx.x, tid = threadIdx.x;
    const int wv = __builtin_amdgcn_readfirstlane((int)(tid >> 6));
    const int lane = tid & 63;
    const int co0 = wv * 8;

    // ---- stage hin -> s_in[pos][ci]; zero s_d1 (ghost rows/cols) ----
    {
        float4* z1 = (float4*)(dbuf + 7056);
        for (int i = tid; i < 729; i += 256) z1[i] = make_float4(0.f, 0.f, 0.f, 0.f);
        for (int t = tid; t < 1024; t += 256) {
            int c = t & 63, p = t >> 6;
            s_in[p * 68 + c] = hin[(size_t)n * 1024 + c * 16 + p];
        }
    }
    __syncthreads();

    // ---- deconv1: ConvT 64->32 k3 s2 p1, 4x4 -> 7x7, relu ----
    // lane = poff(2b) | pq(1b) | cig(3b): 4 pos-par, 4-co quad, 8-way ci (8 ci).
    {
        const int cig = lane & 7, pq = (lane >> 3) & 1, poff = lane >> 4;
        const int ci0 = cig * 8;
        const int ca = co0 + pq * 4;
        float bd[4];
        #pragma unroll
        for (int u = 0; u < 4; ++u) bd[u] = b_d1[ca + u];

        #pragma unroll
        for (int py = 0; py < 2; ++py) {
            #pragma unroll
            for (int px = 0; px < 2; ++px) {
                const int ny = 4 - py, nx = 4 - px;
                const int P = ny * nx;
                const int na = py ? 2 : 1, nb = px ? 2 : 1;
                // class weights: 4 co x (na*nb taps) x 8 ci
                float4 wd[4][2][2][2];
                #pragma unroll
                for (int u = 0; u < 4; ++u)
                    #pragma unroll
                    for (int a = 0; a < 2; ++a) {
                        if (a >= na) continue;
                        #pragma unroll
                        for (int b = 0; b < 2; ++b) {
                            if (b >= nb) continue;
                            int ky = py ? (a ? 2 : 0) : 1;
                            int kx = px ? (b ? 2 : 0) : 1;
                            const float* wp = wtd1 + ((ca + u) * 9 + ky * 3 + kx) * 64 + ci0;
                            wd[u][a][b][0] = *(const float4*)(wp);
                            wd[u][a][b][1] = *(const float4*)(wp + 4);
                        }
                    }
                const int niter = (P + 3) >> 2;
                for (int it = 0; it < niter; ++it) {
                    int pidx = it * 4 + poff;
                    bool act = pidx < P;
                    int p = act ? pidx : 0;
                    int sy = p / nx, sx = p - sy * nx;
                    float acc[4] = {};
                    #pragma unroll
                    for (int a = 0; a < 2; ++a) {
                        if (a >= na) continue;
                        int iy = py ? (a ? sy : sy + 1) : sy;
                        #pragma unroll
                        for (int b = 0; b < 2; ++b) {
                            if (b >= nb) continue;
                            int ix = px ? (b ? sx : sx + 1) : sx;
                            const float* bp = s_in + (iy * 4 + ix) * 68 + ci0;
                            float4 v0 = *(const float4*)(bp);
                            float4 v1 = *(const float4*)(bp + 4);
                            #pragma unroll
                            for (int u = 0; u < 4; ++u) {
                                dot4a(acc[u], v0, wd[u][a][b][0]);
                                dot4a(acc[u], v1, wd[u][a][b][1]);
                            }
                        }
                    }
                    #pragma unroll
                    for (int u = 0; u < 4; ++u) {
                        acc[u] += __shfl_xor(acc[u], 1);
                        acc[u] += __shfl_xor(acc[u], 2);
                        acc[u] += __shfl_xor(acc[u], 4);
                    }
                    if (cig == 0 && act) {
                        int oy = 2 * sy + py, ox = 2 * sx + px;
                        float4 o;
                        o.x = fmaxf(acc[0] + bd[0], 0.f);
                        o.y = fmaxf(acc[1] + bd[1], 0.f);
                        o.z = fmaxf(acc[2] + bd[2], 0.f);
                        o.w = fmaxf(acc[3] + bd[3], 0.f);
                        *(float4*)(s_d1 + ((oy + 1) * 9 + ox + 1) * 36 + ca) = o;
                    }
                }
            }
        }
    }
    __syncthreads();

    // ---- deconv2: ConvT 32->32 k4 s2 p1, 7x7 -> 14x14, relu ----
    // lane = poff(1b) | px(1b) | py(1b) | pq(1b) | cig(2b): each lane owns one
    // parity class, 4 co, 8 ci; 2-level butterfly over cig.
    {
        const int cig = lane & 3, pq = (lane >> 2) & 1;
        const int py = (lane >> 3) & 1, px = (lane >> 4) & 1, poff = lane >> 5;
        const int ci0 = cig * 8;
        const int ca = co0 + pq * 4;
        float4 w2[4][2][2][2];
        float bd[4];
        #pragma unroll
        for (int u = 0; u < 4; ++u) {
            bd[u] = b_d2[ca + u];
            #pragma unroll
            for (int a = 0; a < 2; ++a)
                #pragma unroll
                for (int b = 0; b < 2; ++b) {
                    int ky = py ? (a ? 2 : 0) : (a ? 3 : 1);
                    int kx = px ? (b ? 2 : 0) : (b ? 3 : 1);
                    const float* wp = wtd2 + ((ca + u) * 16 + ky * 4 + kx) * 32 + ci0;
                    w2[u][a][b][0] = *(const float4*)(wp);
                    w2[u][a][b][1] = *(const float4*)(wp + 4);
                }
        }
        for (int it = 0; it < 25; ++it) {
            int pidx = it * 2 + poff;
            bool act = pidx < 49;
            int sp = act ? pidx : 0;
            int sy = sp / 7, sx = sp - sy * 7;
            float acc[4] = {};
            #pragma unroll
            for (int a = 0; a < 2; ++a) {
                int iy = py ? (a ? sy : sy + 1) : (a ? sy - 1 : sy);
                #pragma unroll
                for (int b = 0; b < 2; ++b) {
                    int ix = px ? (b ? sx : sx + 1) : (b ? sx - 1 : sx);
                    const float* bp = s_d1 + ((iy + 1) * 9 + ix + 1) * 36 + ci0;
                    float4 v0 = *(const float4*)(bp);
                    float4 v1 = *(const float4*)(bp + 4);
                    #pragma unroll
                    for (int u = 0; u < 4; ++u) {
                        dot4a(acc[u], v0, w2[u][a][b][0]);
                        dot4a(acc[u], v1, w2[u][a][b][1]);
                    }
                }
            }
            #pragma unroll
            for (int u = 0; u < 4; ++u) {
                acc[u] += __shfl_xor(acc[u], 1);
                acc[u] += __shfl_xor(acc[u], 2);
            }
            if (cig == 0 && act) {
                int oy = 2 * sy + py, ox = 2 * sx + px;
                float4 o;
                o.x = fmaxf(acc[0] + bd[0], 0.f);
                o.y = fmaxf(acc[1] + bd[1], 0.f);
                o.z = fmaxf(acc[2] + bd[2], 0.f);
                o.w = fmaxf(acc[3] + bd[3], 0.f);
                *(float4*)(s_d2 + (oy * 14 + ox) * 36 + ca) = o;
            }
        }
    }
    __syncthreads();

    // ---- deconv3 phase 1: P[t][pos] = sum_ci d2[ci,pos] * w3[ci,t] ----
    // lane = pp(4b) | tq(2b); each lane: 1 pos x 4 taps x 32 ci.
    {
        const int pp = lane & 15, tq = lane >> 4;
        float4 w3[4][8];
        #pragma unroll
        for (int j = 0; j < 4; ++j)
            #pragma unroll
            for (int q = 0; q < 8; ++q)
                w3[j][q] = *(const float4*)(wtd3 + (tq * 4 + j) * 32 + q * 4);
        #pragma unroll
        for (int r = 0; r < 4; ++r) {
            int p = r * 64 + wv * 16 + pp;
            if (p < 196) {
                const float* bp = s_d2 + p * 36;
                float4 v[8];
                #pragma unroll
                for (int q = 0; q < 8; ++q) v[q] = *(const float4*)(bp + q * 4);
                #pragma unroll
                for (int j = 0; j < 4; ++j) {
                    float acc = 0.f;
                    #pragma unroll
                    for (int q = 0; q < 8; ++q) dot4a(acc, v[q], w3[j][q]);
                    sP[(tq * 4 + j) * 196 + p] = acc;
                }
            }
        }
    }
    __syncthreads();

    // ---- deconv3 phase 2: x_hat = sigmoid(b + 4 masked P lookups) ----
    {
        const float bd3 = b_d3[0];
        #pragma unroll
        for (int t = 0; t < 4; ++t) {
            int o = t * 256 + tid;
            if (o < 784) {
                int oy = o / 28, ox = o - oy * 28;
                int py = oy & 1, px = ox & 1, sy = oy >> 1, sx = ox >> 1;
                float acc = bd3;
                #pragma unroll
                for (int a = 0; a < 2; ++a) {
                    int ky = py ? (a ? 2 : 0) : (a ? 3 : 1);
                    int iy = py ? (a ? sy : sy + 1) : (a ? sy - 1 : sy);
                    bool vy = (unsigned)iy < 14u;
                    #pragma unroll
                    for (int b = 0; b < 2; ++b) {
                        int kx = px ? (b ? 2 : 0) : (b ? 3 : 1);
                        int ix = px ? (b ? sx : sx + 1) : (b ? sx - 1 : sx);
                        if (vy && (unsigned)ix < 14u)
                            acc += sP[(ky * 4 + kx) * 196 + iy * 14 + ix];
                    }
                }
                xhat[(size_t)n * 784 + o] = 1.f / (1.f + expf(-acc));
            }
        }
    }
}

extern "C" void kernel_launch(void* const* d_in, const int* in_sizes, int n_in,
                              void* d_out, int out_size, void* d_ws, size_t ws_size,
                              hipStream_t stream) {
    const float* x     = (const float*)d_in[0];
    const float* eps   = (const float*)d_in[1];
    const float* w_c1  = (const float*)d_in[2];
    const float* b_c1  = (const float*)d_in[3];
    const float* w_c2  = (const float*)d_in[4];
    const float* b_c2  = (const float*)d_in[5];
    const float* w_c3  = (const float*)d_in[6];
    const float* b_c3  = (const float*)d_in[7];
    const float* w_fc1 = (const float*)d_in[8];
    const float* b_fc1 = (const float*)d_in[9];
    const float* w_mu  = (const float*)d_in[10];
    const float* b_mu  = (const float*)d_in[11];
    const float* w_ls  = (const float*)d_in[12];
    const float* b_ls  = (const float*)d_in[13];
    const float* w_fc2 = (const float*)d_in[14];
    const float* b_fc2 = (const float*)d_in[15];
    const float* w_fc3 = (const float*)d_in[16];
    const float* b_fc3 = (const float*)d_in[17];
    const float* w_d1  = (const float*)d_in[18];
    const float* b_d1  = (const float*)d_in[19];
    const float* w_d2  = (const float*)d_in[20];
    const float* b_d2  = (const float*)d_in[21];
    const float* w_d3  = (const float*)d_in[22];
    const float* b_d3  = (const float*)d_in[23];

    float* out = (float*)d_out;
    float* x_hat  = out;                  // 4096*784
    float* mu_out = out + 4096 * 784;     // 4096*20
    float* ls_out = mu_out + 4096 * 20;   // 4096*20

    float* buf1 = (float*)d_ws;           // 4096*1024 (h3 / fc3 out); zlat reuses head
    float* buf2 = buf1 + 4096 * 1024;     // 4096*256  (fc1 out / fc2 out)
    float* zlat = buf1;                   // 4096*20, live only between mulsrev and fc2
    float* wt2  = buf2 + 4096 * 256;      // 16384
    float* wt3  = wt2 + 16384;            // 18432
    float* wtd1 = wt3 + 18432;            // 18432
    float* wtd2 = wtd1 + 18432;           // 16384
    float* wtd3 = wtd2 + 16384;           // 512

    tr_kernel<<<72, 256, 0, stream>>>(w_c2, w_c3, w_d1, w_d2, w_d3, wt2, wt3, wtd1, wtd2, wtd3);
    enc_kernel<<<BATCH, 256, 0, stream>>>(x, w_c1, b_c1, wt2, b_c2, wt3, b_c3, buf1);
    gemm_nt<true><<<dim3(256 / 64, BATCH / 64), 256, 0, stream>>>(buf1, w_fc1, b_fc1, buf2, BATCH, 256, 1024);
    mulsrev_kernel<<<(BATCH * 20) / 256, 256, 0, stream>>>(buf2, w_mu, b_mu, w_ls, b_ls, eps, mu_out, ls_out, zlat);
    fc2_kernel<<<BATCH, 256, 0, stream>>>(zlat, w_fc2, b_fc2, buf2);
    gemm_nt<true><<<dim3(1024 / 64, BATCH / 64), 256, 0, stream>>>(buf2, w_fc3, b_fc3, buf1, BATCH, 1024, 256);
    dec_kernel<<<BATCH, 256, 0, stream>>>(buf1, wtd1, b_d1, wtd2, b_d2, wtd3, b_d3, x_hat);
}